// Round 3
// baseline (442.053 us; speedup 1.0000x reference)
//
#include <hip/hip_runtime.h>
#include <hip/hip_bf16.h>

typedef unsigned short u16;
typedef unsigned int u32;
typedef __attribute__((ext_vector_type(8))) short short8;
typedef __attribute__((ext_vector_type(8))) __bf16 bf16x8;
typedef __attribute__((ext_vector_type(4))) float f32x4;

// ---------- helpers ----------
__device__ __forceinline__ float bf2f(u16 u) {
    union { float f; unsigned int i; } v; v.i = ((unsigned int)u) << 16; return v.f;
}
__device__ __forceinline__ u16 f2bf(float f) {
    __hip_bfloat16 h = __float2bfloat16(f);
    return *reinterpret_cast<u16*>(&h);
}
__device__ __forceinline__ float silu_f(float v) { return v / (1.0f + __expf(-v)); }
// XOR swizzle for row-major [rows][128] bf16 tiles (256B rows): spreads the
// stride-256B column-fragment reads across banks (guide G4 / T2).
__device__ __forceinline__ unsigned swz(unsigned row, unsigned colbyte) {
    return row * 256u + (colbyte ^ ((row & 7u) << 4));
}
__device__ __forceinline__ f32x4 MFMA(short8 a, short8 b, f32x4 c) {
    return __builtin_amdgcn_mfma_f32_16x16x32_bf16(
        __builtin_bit_cast(bf16x8, a), __builtin_bit_cast(bf16x8, b), c, 0, 0, 0);
}

// ---------- workspace layout (u16 element offsets) ----------
#define OFF_W1T 0        // [5][128][128] w1T[l][cout][cin]
#define OFF_W2T 81920    // [5][128][128]
#define OFF_WGT 163840   // [3][128][128] wgT[j][cout][cin]
#define OFF_TGP 212992   // [384][32]  zero-padded to_grid
#define OFF_FGT 225280   // [32][384]  zero-padded from_grid, transposed
#define OFF_WSB 237568   // [128][128] ws (gating matrix), layout [k][c]
#define OFF_B1B 253952   // [128]
#define OFF_BSB 254080   // [128]
#define OFF_B2B 254208   // [128]
#define PREP_TOTAL 254336
#define OFF_FLAG 254336  // u32 flag at byte offset 2*254336

// ---- dtype detector: 1 = device buffers are bf16, 0 = float32 ----
// Even-indexed u16s of x: genuine values if bf16 (|v| in [1e-4,100] ~always),
// mantissa-low garbage if f32 (uniform exponent -> ~8% in range).
__global__ void detect_kernel(const void* __restrict__ x, u32* __restrict__ flagp) {
    int tid = threadIdx.x;  // 64 threads
    const u16* p = (const u16*)x;
    int cnt = 0;
    #pragma unroll
    for (int j = 0; j < 8; ++j) {
        float v = fabsf(bf2f(p[2 * (tid * 8 + j)]));
        if (v >= 1e-4f && v <= 100.0f) ++cnt;
    }
    #pragma unroll
    for (int d = 32; d; d >>= 1) cnt += __shfl_down(cnt, d);
    if (tid == 0) *flagp = (cnt >= 256) ? 1u : 0u;
}

__global__ void prep_kernel(const void* __restrict__ w1, const void* __restrict__ wg1,
                            const void* __restrict__ wg2, const void* __restrict__ wg3,
                            const void* __restrict__ w2, const void* __restrict__ tg,
                            const void* __restrict__ fg, const void* __restrict__ wsm,
                            const void* __restrict__ b1, const void* __restrict__ bs,
                            const void* __restrict__ b2,
                            u16* __restrict__ wsp, const u32* __restrict__ flagp) {
    const int flag = (int)*flagp;
    int idx = blockIdx.x * 256 + threadIdx.x;
    if (idx >= PREP_TOTAL) return;
    auto ld = [&](const void* p, int s) -> u16 {
        return flag ? ((const u16*)p)[s] : f2bf(((const float*)p)[s]);
    };
    if (idx < OFF_W2T) {
        int l = idx >> 14, c = (idx >> 7) & 127, k = idx & 127;
        wsp[idx] = ld(w1, (l << 14) + (k << 7) + c);
    } else if (idx < OFF_WGT) {
        int j = idx - OFF_W2T;
        int l = j >> 14, c = (j >> 7) & 127, k = j & 127;
        wsp[idx] = ld(w2, (l << 14) + (k << 7) + c);
    } else if (idx < OFF_TGP) {
        int j = idx - OFF_WGT;
        int m = j >> 14, c = (j >> 7) & 127, k = j & 127;
        const void* w = (m == 0) ? wg1 : (m == 1) ? wg2 : wg3;
        wsp[idx] = ld(w, (k << 7) + c);
    } else if (idx < OFF_FGT) {
        int j = idx - OFF_TGP;
        int r = j >> 5, i = j & 31;
        wsp[idx] = (r < 324 && i < 25) ? ld(tg, r * 25 + i) : (u16)0;
    } else if (idx < OFF_WSB) {
        int j = idx - OFF_FGT;
        int i = j / 384, r = j % 384;
        wsp[idx] = (i < 25 && r < 324) ? ld(fg, r * 25 + i) : (u16)0;
    } else if (idx < OFF_B1B) {
        wsp[idx] = ld(wsm, idx - OFF_WSB);
    } else if (idx < OFF_BSB) {
        wsp[idx] = ld(b1, idx - OFF_B1B);
    } else if (idx < OFF_B2B) {
        wsp[idx] = ld(bs, idx - OFF_BSB);
    } else {
        wsp[idx] = ld(b2, idx - OFF_B2B);
    }
}

// One block per sample n. 256 threads = 4 waves. Fully fused pipeline:
// gating -> so3lin1 -> {to_grid -> MLP(3) -> from_grid} streamed in 4 chunks
// of 96 grid rows -> so3lin2.  All intermediates in LDS (76 KB -> 2 blk/CU).
__global__ __launch_bounds__(256, 2) void ffn_kernel(
    const void* __restrict__ xin, const u16* __restrict__ wsp,
    void* __restrict__ outp) {
    const u16* w1T = wsp + OFF_W1T;
    const u16* w2T = wsp + OFF_W2T;
    const u16* wgT = wsp + OFF_WGT;
    const u16* tgp = wsp + OFF_TGP;
    const u16* fgT = wsp + OFF_FGT;
    const u16* wsb = wsp + OFF_WSB;
    const u16* b1b = wsp + OFF_B1B;
    const u16* bsb = wsp + OFF_BSB;
    const u16* b2b = wsp + OFF_B2B;
    const int flag = (int)*(const u32*)(wsp + OFF_FLAG);

    __shared__ u16 xs[32 * 128];    // swizzled row-major: x, later reused for h2
    __shared__ u16 hsT[128 * 56];   // h transposed [c][i], i padded to 56 (zeros)
    __shared__ u16 gA[96 * 128];    // swizzled row-major grid chunk
    __shared__ u16 gB[128 * 120];   // dual use: swz row-major [96][128] OR gT [c][120]

    const int tid = threadIdx.x;
    const int w = tid >> 6;
    const int lane = tid & 63;
    const int lq = lane >> 4;   // quarter-wave id (K-slot / row-block)
    const int lr = lane & 15;   // lane within quarter (M row / N col)
    const int n = blockIdx.x;

    char* xs_b = reinterpret_cast<char*>(xs);
    char* gA_b = reinterpret_cast<char*>(gA);
    char* gB_b = reinterpret_cast<char*>(gB);
    const short8 zero8 = {0, 0, 0, 0, 0, 0, 0, 0};

    // ---- P0: stage x[n] as bf16 (swizzled; rows 25..31 zero); zero hsT ----
    {
        #pragma unroll
        for (int v = 0; v < 4; ++v) {
            int idx = tid + v * 256;          // 1024 x (4 bf16) = [32][128]
            int row = idx >> 5, c4 = idx & 31;
            ushort4 val = make_ushort4(0, 0, 0, 0);
            if (row < 25) {
                if (flag) {
                    val = *reinterpret_cast<const ushort4*>(
                        (const u16*)xin + (size_t)n * 3200 + row * 128 + c4 * 4);
                } else {
                    float4 f = *reinterpret_cast<const float4*>(
                        (const float*)xin + (size_t)n * 3200 + row * 128 + c4 * 4);
                    val.x = f2bf(f.x); val.y = f2bf(f.y);
                    val.z = f2bf(f.z); val.w = f2bf(f.w);
                }
            }
            *reinterpret_cast<ushort4*>(xs_b + swz(row, c4 * 8)) = val;
        }
        unsigned int* hz = reinterpret_cast<unsigned int*>(hsT);
        for (int i = tid; i < 3584; i += 256) hz[i] = 0;
    }
    __syncthreads();

    // ---- P1: gating (threads 0..127, VALU) + so3-linear1 (MFMA, all waves) ----
    float gating_val = 0.f;
    if (tid < 128) {
        float acc = bf2f(bsb[tid]);
        for (int k = 0; k < 128; ++k) {
            float xv = bf2f(*reinterpret_cast<const u16*>(xs_b + swz(0, k * 2)));
            acc += xv * bf2f(wsb[k * 128 + tid]);
        }
        gating_val = silu_f(acc);
    }
    {
        const int m0[5] = {0, 1, 4, 9, 16};
        const int ml[5] = {1, 3, 5, 7, 9};
        #pragma unroll
        for (int l = 0; l < 5; ++l) {
            bool valid = lr < ml[l];
            #pragma unroll
            for (int nn = 0; nn < 2; ++nn) {
                int c = (w + nn * 4) * 16 + lr;
                f32x4 acc = {0.f, 0.f, 0.f, 0.f};
                #pragma unroll
                for (int ks = 0; ks < 4; ++ks) {
                    short8 av = *reinterpret_cast<const short8*>(
                        xs_b + swz(m0[l] + lr, (ks * 32 + lq * 8) * 2));
                    short8 a = valid ? av : zero8;
                    short8 b = *reinterpret_cast<const short8*>(
                        w1T + ((l * 128 + c) * 128 + ks * 32 + lq * 8));
                    acc = MFMA(a, b, acc);
                }
                #pragma unroll
                for (int r = 0; r < 4; ++r) {
                    int mm = lq * 4 + r;
                    if (mm < ml[l]) {
                        int i = m0[l] + mm;
                        float v2 = acc[r] + ((i == 0) ? bf2f(b1b[c]) : 0.f);
                        hsT[c * 56 + i] = f2bf(v2);
                    }
                }
            }
        }
    }
    __syncthreads();

    // ---- P2: stream grid rows in 4 chunks of 96 ----
    f32x4 facc[2][2];
    #pragma unroll
    for (int i = 0; i < 2; ++i)
        #pragma unroll
        for (int j = 0; j < 2; ++j) facc[i][j] = f32x4{0.f, 0.f, 0.f, 0.f};

    for (int ch = 0; ch < 4; ++ch) {
        // (a) to_grid: gA[row][c] = sum_i tgp[ch*96+row][i] * h[i][c]
        {
            short8 bh[2];
            #pragma unroll
            for (int nn = 0; nn < 2; ++nn) {
                int cc = (w * 2 + nn) * 16 + lr;
                bh[nn] = *reinterpret_cast<const short8*>(&hsT[cc * 56 + lq * 8]);
            }
            #pragma unroll
            for (int mt = 0; mt < 6; ++mt) {
                short8 a = *reinterpret_cast<const short8*>(
                    tgp + (ch * 96 + mt * 16 + lr) * 32 + lq * 8);
                #pragma unroll
                for (int nn = 0; nn < 2; ++nn) {
                    int cc = (w * 2 + nn) * 16 + lr;
                    f32x4 acc = MFMA(a, bh[nn], f32x4{0.f, 0.f, 0.f, 0.f});
                    #pragma unroll
                    for (int r = 0; r < 4; ++r) {
                        int row = mt * 16 + lq * 4 + r;
                        *reinterpret_cast<u16*>(gA_b + swz(row, cc * 2)) = f2bf(acc[r]);
                    }
                }
            }
        }
        __syncthreads();

        // (b,c,d) grid MLP: gA -> gB (silu) -> gA (silu) -> gT (in gB, transposed)
        #pragma unroll
        for (int ly = 0; ly < 3; ++ly) {
            char* src = (ly == 1) ? gB_b : gA_b;
            const u16* wT = wgT + ly * 16384;
            short8 bfr[2][4];
            #pragma unroll
            for (int nn = 0; nn < 2; ++nn) {
                int cc = (w * 2 + nn) * 16 + lr;
                #pragma unroll
                for (int ks = 0; ks < 4; ++ks)
                    bfr[nn][ks] = *reinterpret_cast<const short8*>(
                        wT + cc * 128 + ks * 32 + lq * 8);
            }
            #pragma unroll
            for (int mt = 0; mt < 6; ++mt) {
                short8 af[4];
                #pragma unroll
                for (int ks = 0; ks < 4; ++ks)
                    af[ks] = *reinterpret_cast<const short8*>(
                        src + swz(mt * 16 + lr, (ks * 32 + lq * 8) * 2));
                #pragma unroll
                for (int nn = 0; nn < 2; ++nn) {
                    int cc = (w * 2 + nn) * 16 + lr;
                    f32x4 acc = f32x4{0.f, 0.f, 0.f, 0.f};
                    #pragma unroll
                    for (int ks = 0; ks < 4; ++ks) acc = MFMA(af[ks], bfr[nn][ks], acc);
                    if (ly < 2) {
                        char* dst = (ly == 0) ? gB_b : gA_b;
                        #pragma unroll
                        for (int r = 0; r < 4; ++r) {
                            int row = mt * 16 + lq * 4 + r;
                            *reinterpret_cast<u16*>(dst + swz(row, cc * 2)) =
                                f2bf(silu_f(acc[r]));
                        }
                    } else {  // layer 3 raw, transposed into gT[c][row] (stride 120)
                        ushort4 pk;
                        pk.x = f2bf(acc[0]); pk.y = f2bf(acc[1]);
                        pk.z = f2bf(acc[2]); pk.w = f2bf(acc[3]);
                        *reinterpret_cast<ushort4*>(&gB[cc * 120 + mt * 16 + lq * 4]) = pk;
                    }
                }
            }
            __syncthreads();
        }

        // (e) from_grid partial: facc[i-tile][n-tile] += fgT[i][r] * g3[r][c]
        #pragma unroll
        for (int mt = 0; mt < 2; ++mt) {
            #pragma unroll
            for (int ks = 0; ks < 3; ++ks) {
                short8 a = *reinterpret_cast<const short8*>(
                    fgT + (mt * 16 + lr) * 384 + ch * 96 + ks * 32 + lq * 8);
                #pragma unroll
                for (int nn = 0; nn < 2; ++nn) {
                    int cc = (w * 2 + nn) * 16 + lr;
                    short8 b = *reinterpret_cast<const short8*>(
                        &gB[cc * 120 + ks * 32 + lq * 8]);
                    facc[mt][nn] = MFMA(a, b, facc[mt][nn]);
                }
            }
        }
        // no barrier needed: next (a) writes only gA; the barrier after (a)
        // protects gB before any wave reaches the MLP again.
    }

    // ---- P3: h2 -> xs (reuse), overwrite row0 with gating, so3-linear2 ----
    #pragma unroll
    for (int mt = 0; mt < 2; ++mt) {
        #pragma unroll
        for (int nn = 0; nn < 2; ++nn) {
            int cc = (w * 2 + nn) * 16 + lr;
            #pragma unroll
            for (int r = 0; r < 4; ++r) {
                int row = mt * 16 + lq * 4 + r;
                *reinterpret_cast<u16*>(xs_b + swz(row, cc * 2)) = f2bf(facc[mt][nn][r]);
            }
        }
    }
    __syncthreads();
    if (tid < 128)
        *reinterpret_cast<u16*>(xs_b + swz(0, tid * 2)) = f2bf(gating_val);
    __syncthreads();

    {
        const int m0[5] = {0, 1, 4, 9, 16};
        const int ml[5] = {1, 3, 5, 7, 9};
        #pragma unroll
        for (int l = 0; l < 5; ++l) {
            bool valid = lr < ml[l];
            #pragma unroll
            for (int nn = 0; nn < 2; ++nn) {
                int c = (w + nn * 4) * 16 + lr;
                f32x4 acc = {0.f, 0.f, 0.f, 0.f};
                #pragma unroll
                for (int ks = 0; ks < 4; ++ks) {
                    short8 av = *reinterpret_cast<const short8*>(
                        xs_b + swz(m0[l] + lr, (ks * 32 + lq * 8) * 2));
                    short8 a = valid ? av : zero8;
                    short8 b = *reinterpret_cast<const short8*>(
                        w2T + ((l * 128 + c) * 128 + ks * 32 + lq * 8));
                    acc = MFMA(a, b, acc);
                }
                #pragma unroll
                for (int r = 0; r < 4; ++r) {
                    int mm = lq * 4 + r;
                    if (mm < ml[l]) {
                        int i = m0[l] + mm;
                        float v2 = acc[r] + ((i == 0) ? bf2f(b2b[c]) : 0.f);
                        size_t o = (size_t)n * 3200 + i * 128 + c;
                        if (flag) ((u16*)outp)[o] = f2bf(v2);
                        else      ((float*)outp)[o] = v2;
                    }
                }
            }
        }
    }
}

extern "C" void kernel_launch(void* const* d_in, const int* in_sizes, int n_in,
                              void* d_out, int out_size, void* d_ws, size_t ws_size,
                              hipStream_t stream) {
    const void* x   = d_in[0];
    const void* w1  = d_in[1];
    const void* b1  = d_in[2];
    const void* wsm = d_in[3];
    const void* bs  = d_in[4];
    const void* wg1 = d_in[5];
    const void* wg2 = d_in[6];
    const void* wg3 = d_in[7];
    const void* w2  = d_in[8];
    const void* b2  = d_in[9];
    const void* tg  = d_in[10];
    const void* fg  = d_in[11];
    u16* wsp = (u16*)d_ws;
    u32* flagp = (u32*)(wsp + OFF_FLAG);

    detect_kernel<<<1, 64, 0, stream>>>(x, flagp);
    prep_kernel<<<(PREP_TOTAL + 255) / 256, 256, 0, stream>>>(
        w1, wg1, wg2, wg3, w2, tg, fg, wsm, b1, bs, b2, wsp, flagp);
    ffn_kernel<<<2048, 256, 0, stream>>>(x, wsp, d_out);
}

// Round 4
// 284.610 us; speedup vs baseline: 1.5532x; 1.5532x over previous
//
#include <hip/hip_runtime.h>
#include <hip/hip_bf16.h>

typedef unsigned short u16;
typedef unsigned int u32;
typedef __attribute__((ext_vector_type(8))) short short8;
typedef __attribute__((ext_vector_type(8))) __bf16 bf16x8;
typedef __attribute__((ext_vector_type(4))) float f32x4;

// ---------- helpers ----------
__device__ __forceinline__ float bf2f(u16 u) {
    union { float f; unsigned int i; } v; v.i = ((unsigned int)u) << 16; return v.f;
}
__device__ __forceinline__ u16 f2bf(float f) {
    __hip_bfloat16 h = __float2bfloat16(f);
    return *reinterpret_cast<u16*>(&h);
}
__device__ __forceinline__ float silu_f(float v) { return v / (1.0f + __expf(-v)); }
// XOR swizzle for row-major [rows][128] bf16 tiles (256B rows).
__device__ __forceinline__ unsigned swz(unsigned row, unsigned colbyte) {
    return row * 256u + (colbyte ^ ((row & 7u) << 4));
}
__device__ __forceinline__ f32x4 MFMA(short8 a, short8 b, f32x4 c) {
    return __builtin_amdgcn_mfma_f32_16x16x32_bf16(
        __builtin_bit_cast(bf16x8, a), __builtin_bit_cast(bf16x8, b), c, 0, 0, 0);
}

#define SW1 40   // hw1T row stride (u16): 80B -> 16B-aligned frags, 2-way banks
#define SGT 72   // gT   row stride (u16): 144B -> 16B-aligned frags, 2-way banks

// ---------- workspace layout (u16 element offsets) ----------
#define OFF_W1T 0        // [5][128][128] w1T[l][cout][cin]
#define OFF_W2T 81920    // [5][128][128]
#define OFF_WGT 163840   // [3][128][128] wgT[j][cout][cin]
#define OFF_TGP 212992   // [384][32]  zero-padded to_grid
#define OFF_FGT 225280   // [32][384]  zero-padded from_grid, transposed
#define OFF_WSB 237568   // [128][128] wsT[cout][cin] (gating matrix, transposed)
#define OFF_B1B 253952   // [128]
#define OFF_BSB 254080   // [128]
#define OFF_B2B 254208   // [128]
#define PREP_TOTAL 254336
#define OFF_FLAG 254336  // u32 flag

// ---- dtype detector: 1 = device buffers are bf16, 0 = float32 ----
__global__ void detect_kernel(const void* __restrict__ x, u32* __restrict__ flagp) {
    int tid = threadIdx.x;  // 64 threads
    const u16* p = (const u16*)x;
    int cnt = 0;
    #pragma unroll
    for (int j = 0; j < 8; ++j) {
        float v = fabsf(bf2f(p[2 * (tid * 8 + j)]));
        if (v >= 1e-4f && v <= 100.0f) ++cnt;
    }
    #pragma unroll
    for (int d = 32; d; d >>= 1) cnt += __shfl_down(cnt, d);
    if (tid == 0) *flagp = (cnt >= 256) ? 1u : 0u;
}

__global__ void prep_kernel(const void* __restrict__ w1, const void* __restrict__ wg1,
                            const void* __restrict__ wg2, const void* __restrict__ wg3,
                            const void* __restrict__ w2, const void* __restrict__ tg,
                            const void* __restrict__ fg, const void* __restrict__ wsm,
                            const void* __restrict__ b1, const void* __restrict__ bs,
                            const void* __restrict__ b2,
                            u16* __restrict__ wsp, const u32* __restrict__ flagp) {
    const int flag = (int)*flagp;
    int idx = blockIdx.x * 256 + threadIdx.x;
    if (idx >= PREP_TOTAL) return;
    auto ld = [&](const void* p, int s) -> u16 {
        return flag ? ((const u16*)p)[s] : f2bf(((const float*)p)[s]);
    };
    if (idx < OFF_W2T) {
        int l = idx >> 14, c = (idx >> 7) & 127, k = idx & 127;
        wsp[idx] = ld(w1, (l << 14) + (k << 7) + c);
    } else if (idx < OFF_WGT) {
        int j = idx - OFF_W2T;
        int l = j >> 14, c = (j >> 7) & 127, k = j & 127;
        wsp[idx] = ld(w2, (l << 14) + (k << 7) + c);
    } else if (idx < OFF_TGP) {
        int j = idx - OFF_WGT;
        int m = j >> 14, c = (j >> 7) & 127, k = j & 127;
        const void* w = (m == 0) ? wg1 : (m == 1) ? wg2 : wg3;
        wsp[idx] = ld(w, (k << 7) + c);
    } else if (idx < OFF_FGT) {
        int j = idx - OFF_TGP;
        int r = j >> 5, i = j & 31;
        wsp[idx] = (r < 324 && i < 25) ? ld(tg, r * 25 + i) : (u16)0;
    } else if (idx < OFF_WSB) {
        int j = idx - OFF_FGT;
        int i = j / 384, r = j % 384;
        wsp[idx] = (i < 25 && r < 324) ? ld(fg, r * 25 + i) : (u16)0;
    } else if (idx < OFF_B1B) {
        int j = idx - OFF_WSB;     // j = c*128 + k ; wsT[c][k] = ws[k][c]
        wsp[idx] = ld(wsm, ((j & 127) << 7) + (j >> 7));
    } else if (idx < OFF_BSB) {
        wsp[idx] = ld(b1, idx - OFF_B1B);
    } else if (idx < OFF_B2B) {
        wsp[idx] = ld(bs, idx - OFF_BSB);
    } else {
        wsp[idx] = ld(b2, idx - OFF_B2B);
    }
}

// Fused pipeline with the algebraic fold:
//   h   = so3lin1(x)                  (25x128)
//   gate= silu(x0@ws+bs)              (128)   [MFMA, lanes lq==0]
//   hw1 = h @ wg1                     (25x128; fold of to_grid+layer1)
//   per 64-row grid chunk (6 chunks, rows padded to 384):
//     a1 = silu(tg_ch @ hw1)          (64x128)
//     a2 = silu(a1 @ wg2)             -> stored transposed gT[c][row]
//     facc += fgT_ch @ a2             (25x128 accum in regs; fold of wg3)
//   h2  = facc @ wg3 ; row0 <- gate
//   out = so3lin2(h2) + b2(row0)
// LDS 44 KB -> 3 blocks/CU.
__global__ __launch_bounds__(256, 3) void ffn_kernel(
    const void* __restrict__ xin, const u16* __restrict__ wsp,
    void* __restrict__ outp) {
    const u16* w1T  = wsp + OFF_W1T;
    const u16* w2T  = wsp + OFF_W2T;
    const u16* wg1T = wsp + OFF_WGT;
    const u16* wg2T = wsp + OFF_WGT + 16384;
    const u16* wg3T = wsp + OFF_WGT + 32768;
    const u16* tgp  = wsp + OFF_TGP;
    const u16* fgT  = wsp + OFF_FGT;
    const u16* wsT  = wsp + OFF_WSB;
    const u16* b1b  = wsp + OFF_B1B;
    const u16* bsb  = wsp + OFF_BSB;
    const u16* b2b  = wsp + OFF_B2B;
    const int flag = (int)*(const u32*)(wsp + OFF_FLAG);

    __shared__ u16 ldsA[64 * 128];   // phase1: xs(rows0-31)|hs(rows32-63);
                                     // chunks: gA[64][128]; end: h2p|h2f
    __shared__ u16 hw1T[128 * SW1];  // hw1 transposed [d][i], i<32 (pad 40)
    __shared__ u16 gTl[128 * SGT];   // a2 transposed [c][row], row<64 (pad 72)

    const int tid = threadIdx.x;
    const int w = tid >> 6;
    const int lane = tid & 63;
    const int lq = lane >> 4;   // quarter-wave (K-slot / C-row-block)
    const int lr = lane & 15;   // lane within quarter (A-row / C-col)
    const int n = blockIdx.x;

    char* gA_b = reinterpret_cast<char*>(ldsA);   // rows 0..63
    char* xs_b = gA_b;                            // alias rows 0..31
    char* hs_b = gA_b + 32 * 256;                 // alias rows 32..63 (local rows 0..31)
    const short8 zero8 = {0, 0, 0, 0, 0, 0, 0, 0};

    // ---- P0: stage x[n] as bf16 into xs (swizzled; rows 25..31 zero);
    //          zero hs rows 25..31 (so3lin1 never writes them) ----
    {
        #pragma unroll
        for (int v = 0; v < 4; ++v) {
            int idx = tid + v * 256;          // 1024 x (4 bf16) = [32][128]
            int row = idx >> 5, c4 = idx & 31;
            ushort4 val = make_ushort4(0, 0, 0, 0);
            if (row < 25) {
                if (flag) {
                    val = *reinterpret_cast<const ushort4*>(
                        (const u16*)xin + (size_t)n * 3200 + row * 128 + c4 * 4);
                } else {
                    float4 f = *reinterpret_cast<const float4*>(
                        (const float*)xin + (size_t)n * 3200 + row * 128 + c4 * 4);
                    val.x = f2bf(f.x); val.y = f2bf(f.y);
                    val.z = f2bf(f.z); val.w = f2bf(f.w);
                }
            }
            *reinterpret_cast<ushort4*>(xs_b + swz(row, c4 * 8)) = val;
        }
        for (int i = tid; i < 448; i += 256)          // 7 rows * 256B
            ((u32*)(hs_b + 25 * 256))[i] = 0;
    }
    __syncthreads();

    // ---- P1: gating GEMM (reads xs row0) + so3lin1 (xs -> hs) ----
    float gate_v[2] = {0.f, 0.f};     // valid on lanes with lq==0
    {
        #pragma unroll
        for (int nn = 0; nn < 2; ++nn) {
            int cc = (w * 2 + nn) * 16 + lr;
            f32x4 acc = {0.f, 0.f, 0.f, 0.f};
            #pragma unroll
            for (int ks = 0; ks < 4; ++ks) {
                short8 a = zero8;
                if (lr == 0)
                    a = *reinterpret_cast<const short8*>(
                        xs_b + swz(0, (ks * 32 + lq * 8) * 2));
                short8 b = *reinterpret_cast<const short8*>(
                    wsT + cc * 128 + ks * 32 + lq * 8);
                acc = MFMA(a, b, acc);
            }
            gate_v[nn] = silu_f(acc[0] + bf2f(bsb[cc]));
        }
        const int m0[5] = {0, 1, 4, 9, 16};
        const int ml[5] = {1, 3, 5, 7, 9};
        #pragma unroll
        for (int l = 0; l < 5; ++l) {
            bool valid = lr < ml[l];
            #pragma unroll
            for (int nn = 0; nn < 2; ++nn) {
                int c = (w * 2 + nn) * 16 + lr;
                f32x4 acc = {0.f, 0.f, 0.f, 0.f};
                #pragma unroll
                for (int ks = 0; ks < 4; ++ks) {
                    short8 av = *reinterpret_cast<const short8*>(
                        xs_b + swz(m0[l] + lr, (ks * 32 + lq * 8) * 2));
                    short8 a = valid ? av : zero8;
                    short8 b = *reinterpret_cast<const short8*>(
                        w1T + (l * 128 + c) * 128 + ks * 32 + lq * 8);
                    acc = MFMA(a, b, acc);
                }
                #pragma unroll
                for (int r = 0; r < 4; ++r) {
                    int mm = lq * 4 + r;
                    if (mm < ml[l]) {
                        int i = m0[l] + mm;
                        float v2 = acc[r] + ((i == 0) ? bf2f(b1b[c]) : 0.f);
                        *reinterpret_cast<u16*>(hs_b + swz(i, c * 2)) = f2bf(v2);
                    }
                }
            }
        }
    }
    __syncthreads();

    // ---- P1.5: hw1 = h @ wg1 -> hw1T[d][i] (rows i>=25 are zero via hs) ----
    {
        #pragma unroll
        for (int mt = 0; mt < 2; ++mt) {
            #pragma unroll
            for (int nn = 0; nn < 2; ++nn) {
                int cc = (w * 2 + nn) * 16 + lr;
                f32x4 acc = {0.f, 0.f, 0.f, 0.f};
                #pragma unroll
                for (int ks = 0; ks < 4; ++ks) {
                    short8 a = *reinterpret_cast<const short8*>(
                        hs_b + swz(mt * 16 + lr, (ks * 32 + lq * 8) * 2));
                    short8 b = *reinterpret_cast<const short8*>(
                        wg1T + cc * 128 + ks * 32 + lq * 8);
                    acc = MFMA(a, b, acc);
                }
                ushort4 pk;
                pk.x = f2bf(acc[0]); pk.y = f2bf(acc[1]);
                pk.z = f2bf(acc[2]); pk.w = f2bf(acc[3]);
                *reinterpret_cast<ushort4*>(&hw1T[cc * SW1 + mt * 16 + lq * 4]) = pk;
            }
        }
    }
    __syncthreads();

    // ---- P2: 6 chunks of 64 grid rows (padded to 384) ----
    f32x4 facc[2][2];
    #pragma unroll
    for (int i = 0; i < 2; ++i)
        #pragma unroll
        for (int j = 0; j < 2; ++j) facc[i][j] = f32x4{0.f, 0.f, 0.f, 0.f};

    for (int ch = 0; ch < 6; ++ch) {
        // (a) a1 = silu(tg_ch @ hw1)  -> gA rows 0..63   (K = 32 i-dim)
        {
            short8 bh[2];
            #pragma unroll
            for (int nn = 0; nn < 2; ++nn) {
                int cc = (w * 2 + nn) * 16 + lr;
                bh[nn] = *reinterpret_cast<const short8*>(&hw1T[cc * SW1 + lq * 8]);
            }
            #pragma unroll
            for (int mt = 0; mt < 4; ++mt) {
                short8 a = *reinterpret_cast<const short8*>(
                    tgp + (ch * 64 + mt * 16 + lr) * 32 + lq * 8);
                #pragma unroll
                for (int nn = 0; nn < 2; ++nn) {
                    int cc = (w * 2 + nn) * 16 + lr;
                    f32x4 acc = MFMA(a, bh[nn], f32x4{0.f, 0.f, 0.f, 0.f});
                    #pragma unroll
                    for (int r = 0; r < 4; ++r) {
                        int row = mt * 16 + lq * 4 + r;
                        *reinterpret_cast<u16*>(gA_b + swz(row, cc * 2)) =
                            f2bf(silu_f(acc[r]));
                    }
                }
            }
        }
        __syncthreads();

        // (b) a2 = silu(a1 @ wg2) -> gTl[c][row]  (transposed, packed stores)
        {
            short8 bfr[2][4];
            #pragma unroll
            for (int nn = 0; nn < 2; ++nn) {
                int cc = (w * 2 + nn) * 16 + lr;
                #pragma unroll
                for (int ks = 0; ks < 4; ++ks)
                    bfr[nn][ks] = *reinterpret_cast<const short8*>(
                        wg2T + cc * 128 + ks * 32 + lq * 8);
            }
            int cc0 = (w * 2) * 16 + lr, cc1 = (w * 2 + 1) * 16 + lr;
            #pragma unroll
            for (int mt = 0; mt < 4; ++mt) {
                f32x4 a0 = {0.f, 0.f, 0.f, 0.f}, a1 = {0.f, 0.f, 0.f, 0.f};
                #pragma unroll
                for (int ks = 0; ks < 4; ++ks) {
                    short8 af = *reinterpret_cast<const short8*>(
                        gA_b + swz(mt * 16 + lr, (ks * 32 + lq * 8) * 2));
                    a0 = MFMA(af, bfr[0][ks], a0);
                    a1 = MFMA(af, bfr[1][ks], a1);
                }
                ushort4 p0, p1;
                p0.x = f2bf(silu_f(a0[0])); p0.y = f2bf(silu_f(a0[1]));
                p0.z = f2bf(silu_f(a0[2])); p0.w = f2bf(silu_f(a0[3]));
                p1.x = f2bf(silu_f(a1[0])); p1.y = f2bf(silu_f(a1[1]));
                p1.z = f2bf(silu_f(a1[2])); p1.w = f2bf(silu_f(a1[3]));
                *reinterpret_cast<ushort4*>(&gTl[cc0 * SGT + mt * 16 + lq * 4]) = p0;
                *reinterpret_cast<ushort4*>(&gTl[cc1 * SGT + mt * 16 + lq * 4]) = p1;
            }
        }
        __syncthreads();

        // (e) facc += fgT_ch @ a2   (A rows = SH coeff i, K = grid rows)
        #pragma unroll
        for (int mt = 0; mt < 2; ++mt) {
            #pragma unroll
            for (int ks = 0; ks < 2; ++ks) {
                short8 a = *reinterpret_cast<const short8*>(
                    fgT + (mt * 16 + lr) * 384 + ch * 64 + ks * 32 + lq * 8);
                #pragma unroll
                for (int nn = 0; nn < 2; ++nn) {
                    int cc = (w * 2 + nn) * 16 + lr;
                    short8 b = *reinterpret_cast<const short8*>(
                        &gTl[cc * SGT + ks * 32 + lq * 8]);
                    facc[mt][nn] = MFMA(a, b, facc[mt][nn]);
                }
            }
        }
        // no barrier: next (a) writes gA only (nobody reads gA until after the
        // (a)-barrier); gTl is protected by the barrier after (a).
    }

    // ---- P3: h2p = facc -> xs area; h2 = h2p @ wg3 (row0 <- gate) -> hs area;
    //          out = so3lin2(h2) ----
    #pragma unroll
    for (int mt = 0; mt < 2; ++mt)
        #pragma unroll
        for (int nn = 0; nn < 2; ++nn) {
            int cc = (w * 2 + nn) * 16 + lr;
            #pragma unroll
            for (int r = 0; r < 4; ++r)
                *reinterpret_cast<u16*>(xs_b + swz(mt * 16 + lq * 4 + r, cc * 2)) =
                    f2bf(facc[mt][nn][r]);
        }
    __syncthreads();

    #pragma unroll
    for (int mt = 0; mt < 2; ++mt)
        #pragma unroll
        for (int nn = 0; nn < 2; ++nn) {
            int cc = (w * 2 + nn) * 16 + lr;
            f32x4 acc = {0.f, 0.f, 0.f, 0.f};
            #pragma unroll
            for (int ks = 0; ks < 4; ++ks) {
                short8 a = *reinterpret_cast<const short8*>(
                    xs_b + swz(mt * 16 + lr, (ks * 32 + lq * 8) * 2));
                short8 b = *reinterpret_cast<const short8*>(
                    wg3T + cc * 128 + ks * 32 + lq * 8);
                acc = MFMA(a, b, acc);
            }
            #pragma unroll
            for (int r = 0; r < 4; ++r) {
                int row = mt * 16 + lq * 4 + r;
                float v = (row == 0) ? gate_v[nn] : acc[r];
                *reinterpret_cast<u16*>(hs_b + swz(row, cc * 2)) = f2bf(v);
            }
        }
    __syncthreads();

    {
        const int m0[5] = {0, 1, 4, 9, 16};
        const int ml[5] = {1, 3, 5, 7, 9};
        #pragma unroll
        for (int l = 0; l < 5; ++l) {
            bool valid = lr < ml[l];
            #pragma unroll
            for (int nn = 0; nn < 2; ++nn) {
                int c = (w * 2 + nn) * 16 + lr;
                f32x4 acc = {0.f, 0.f, 0.f, 0.f};
                #pragma unroll
                for (int ks = 0; ks < 4; ++ks) {
                    short8 av = *reinterpret_cast<const short8*>(
                        hs_b + swz(m0[l] + lr, (ks * 32 + lq * 8) * 2));
                    short8 a = valid ? av : zero8;
                    short8 b = *reinterpret_cast<const short8*>(
                        w2T + (l * 128 + c) * 128 + ks * 32 + lq * 8);
                    acc = MFMA(a, b, acc);
                }
                #pragma unroll
                for (int r = 0; r < 4; ++r) {
                    int mm = lq * 4 + r;
                    if (mm < ml[l]) {
                        int i = m0[l] + mm;
                        float v2 = acc[r] + ((i == 0) ? bf2f(b2b[c]) : 0.f);
                        size_t o = (size_t)n * 3200 + i * 128 + c;
                        if (flag) ((u16*)outp)[o] = f2bf(v2);
                        else      ((float*)outp)[o] = v2;
                    }
                }
            }
        }
    }
}

extern "C" void kernel_launch(void* const* d_in, const int* in_sizes, int n_in,
                              void* d_out, int out_size, void* d_ws, size_t ws_size,
                              hipStream_t stream) {
    const void* x   = d_in[0];
    const void* w1  = d_in[1];
    const void* b1  = d_in[2];
    const void* wsm = d_in[3];
    const void* bs  = d_in[4];
    const void* wg1 = d_in[5];
    const void* wg2 = d_in[6];
    const void* wg3 = d_in[7];
    const void* w2  = d_in[8];
    const void* b2  = d_in[9];
    const void* tg  = d_in[10];
    const void* fg  = d_in[11];
    u16* wsp = (u16*)d_ws;
    u32* flagp = (u32*)(wsp + OFF_FLAG);

    detect_kernel<<<1, 64, 0, stream>>>(x, flagp);
    prep_kernel<<<(PREP_TOTAL + 255) / 256, 256, 0, stream>>>(
        w1, wg1, wg2, wg3, w2, tg, fg, wsm, b1, bs, b2, wsp, flagp);
    ffn_kernel<<<2048, 256, 0, stream>>>(x, wsp, d_out);
}

// Round 5
// 268.412 us; speedup vs baseline: 1.6469x; 1.0604x over previous
//
#include <hip/hip_runtime.h>
#include <hip/hip_bf16.h>

typedef unsigned short u16;
typedef unsigned int u32;
typedef __attribute__((ext_vector_type(8))) short short8;
typedef __attribute__((ext_vector_type(8))) __bf16 bf16x8;
typedef __attribute__((ext_vector_type(4))) float f32x4;

// ---------- helpers ----------
__device__ __forceinline__ float bf2f(u16 u) {
    union { float f; unsigned int i; } v; v.i = ((unsigned int)u) << 16; return v.f;
}
// manual RNE f32->bf16 (values finite; no NaN path needed)
__device__ __forceinline__ u16 f2bf(float f) {
    u32 b = __builtin_bit_cast(u32, f);
    b += 0x7FFFu + ((b >> 16) & 1u);
    return (u16)(b >> 16);
}
// pack two f32 -> two bf16 in one u32 (lo=f0, hi=f1)
__device__ __forceinline__ u32 f2bf2(float f0, float f1) {
    u32 b0 = __builtin_bit_cast(u32, f0);
    u32 b1 = __builtin_bit_cast(u32, f1);
    b0 += 0x7FFFu + ((b0 >> 16) & 1u);
    b1 += 0x7FFFu + ((b1 >> 16) & 1u);
    return (b0 >> 16) | (b1 & 0xFFFF0000u);
}
// fast silu: x * rcp(1+exp(-x))  (~5 ops, rcp 1ulp fine for bf16 outputs)
__device__ __forceinline__ float silu_f(float v) {
    return v * __builtin_amdgcn_rcpf(1.0f + __expf(-v));
}
// XOR swizzle for row-major [rows][128] bf16 tiles (256B rows).
__device__ __forceinline__ unsigned swz(unsigned row, unsigned colbyte) {
    return row * 256u + (colbyte ^ ((row & 7u) << 4));
}
__device__ __forceinline__ f32x4 MFMA(short8 a, short8 b, f32x4 c) {
    return __builtin_amdgcn_mfma_f32_16x16x32_bf16(
        __builtin_bit_cast(bf16x8, a), __builtin_bit_cast(bf16x8, b), c, 0, 0, 0);
}

#define SW1 40   // hw1T row stride (u16): 80B (16B-aligned frags)
#define SGT 72   // gTl  row stride (u16): 144B (16B-aligned frags)

// ---------- workspace layout (u16 element offsets) ----------
#define OFF_W1T 0        // [5][128][128] w1T[l][cout][cin]
#define OFF_W2T 81920    // [5][128][128]
#define OFF_WGT 163840   // [3][128][128] wgT[j][cout][cin]
#define OFF_TGP 212992   // [384][32]  zero-padded to_grid
#define OFF_FGT 225280   // [32][384]  zero-padded from_grid, transposed
#define OFF_WSB 237568   // [128][128] wsT[cout][cin] (gating matrix, transposed)
#define OFF_B1B 253952   // [128]
#define OFF_BSB 254080   // [128]
#define OFF_B2B 254208   // [128]
#define PREP_TOTAL 254336
#define OFF_FLAG 254336  // u32 flag

// ---- dtype detector: 1 = device buffers are bf16, 0 = float32 ----
__global__ void detect_kernel(const void* __restrict__ x, u32* __restrict__ flagp) {
    int tid = threadIdx.x;  // 64 threads
    const u16* p = (const u16*)x;
    int cnt = 0;
    #pragma unroll
    for (int j = 0; j < 8; ++j) {
        float v = fabsf(bf2f(p[2 * (tid * 8 + j)]));
        if (v >= 1e-4f && v <= 100.0f) ++cnt;
    }
    #pragma unroll
    for (int d = 32; d; d >>= 1) cnt += __shfl_down(cnt, d);
    if (tid == 0) *flagp = (cnt >= 256) ? 1u : 0u;
}

__global__ void prep_kernel(const void* __restrict__ w1, const void* __restrict__ wg1,
                            const void* __restrict__ wg2, const void* __restrict__ wg3,
                            const void* __restrict__ w2, const void* __restrict__ tg,
                            const void* __restrict__ fg, const void* __restrict__ wsm,
                            const void* __restrict__ b1, const void* __restrict__ bs,
                            const void* __restrict__ b2,
                            u16* __restrict__ wsp, const u32* __restrict__ flagp) {
    const int flag = (int)*flagp;
    int idx = blockIdx.x * 256 + threadIdx.x;
    if (idx >= PREP_TOTAL) return;
    auto ld = [&](const void* p, int s) -> u16 {
        return flag ? ((const u16*)p)[s] : f2bf(((const float*)p)[s]);
    };
    if (idx < OFF_W2T) {
        int l = idx >> 14, c = (idx >> 7) & 127, k = idx & 127;
        wsp[idx] = ld(w1, (l << 14) + (k << 7) + c);
    } else if (idx < OFF_WGT) {
        int j = idx - OFF_W2T;
        int l = j >> 14, c = (j >> 7) & 127, k = j & 127;
        wsp[idx] = ld(w2, (l << 14) + (k << 7) + c);
    } else if (idx < OFF_TGP) {
        int j = idx - OFF_WGT;
        int m = j >> 14, c = (j >> 7) & 127, k = j & 127;
        const void* w = (m == 0) ? wg1 : (m == 1) ? wg2 : wg3;
        wsp[idx] = ld(w, (k << 7) + c);
    } else if (idx < OFF_FGT) {
        int j = idx - OFF_TGP;
        int r = j >> 5, i = j & 31;
        wsp[idx] = (r < 324 && i < 25) ? ld(tg, r * 25 + i) : (u16)0;
    } else if (idx < OFF_WSB) {
        int j = idx - OFF_FGT;
        int i = j / 384, r = j % 384;
        wsp[idx] = (i < 25 && r < 324) ? ld(fg, r * 25 + i) : (u16)0;
    } else if (idx < OFF_B1B) {
        int j = idx - OFF_WSB;     // j = c*128 + k ; wsT[c][k] = ws[k][c]
        wsp[idx] = ld(wsm, ((j & 127) << 7) + (j >> 7));
    } else if (idx < OFF_BSB) {
        wsp[idx] = ld(b1, idx - OFF_B1B);
    } else if (idx < OFF_B2B) {
        wsp[idx] = ld(bs, idx - OFF_BSB);
    } else {
        wsp[idx] = ld(b2, idx - OFF_B2B);
    }
}

// Fused pipeline; every hot-loop GEMM oriented so epilogues use packed 8B
// LDS stores (operand-swap trick: C fragments along M -> choose M = the
// contiguous dim of the consumer's layout).
__global__ __launch_bounds__(256, 3) void ffn_kernel(
    const void* __restrict__ xin, const u16* __restrict__ wsp,
    void* __restrict__ outp) {
    const u16* w1T  = wsp + OFF_W1T;
    const u16* w2T  = wsp + OFF_W2T;
    const u16* wg1T = wsp + OFF_WGT;
    const u16* wg2T = wsp + OFF_WGT + 16384;
    const u16* wg3T = wsp + OFF_WGT + 32768;
    const u16* tgp  = wsp + OFF_TGP;
    const u16* fgT  = wsp + OFF_FGT;
    const u16* wsT  = wsp + OFF_WSB;
    const u16* b1b  = wsp + OFF_B1B;
    const u16* bsb  = wsp + OFF_BSB;
    const u16* b2b  = wsp + OFF_B2B;
    const int flag = (int)*(const u32*)(wsp + OFF_FLAG);

    __shared__ u16 ldsA[64 * 128];   // P1: xs(rows0-31)+hs(rows32-63);
                                     // chunks: a1R[64][128]; P3: h2p+h2R
    __shared__ u16 hw1T[128 * SW1];  // hw1 transposed [d][i]
    __shared__ u16 gTl[128 * SGT];   // a2 transposed [c2][grow]

    const int tid = threadIdx.x;
    const int w = tid >> 6;
    const int lane = tid & 63;
    const int lq = lane >> 4;
    const int lr = lane & 15;
    const int n = blockIdx.x;

    char* gA_b = reinterpret_cast<char*>(ldsA);   // rows 0..63
    char* xs_b = gA_b;                            // rows 0..31
    char* hs_b = gA_b + 32 * 256;                 // rows 32..63
    const short8 zero8 = {0, 0, 0, 0, 0, 0, 0, 0};
    const int cc0 = (w * 2) * 16 + lr, cc1 = (w * 2 + 1) * 16 + lr;

    // ---- P0: stage x[n] (row-major swizzled; rows 25..31 zero); zero hs tail ----
    {
        #pragma unroll
        for (int v = 0; v < 4; ++v) {
            int idx = tid + v * 256;
            int row = idx >> 5, c4 = idx & 31;
            ushort4 val = make_ushort4(0, 0, 0, 0);
            if (row < 25) {
                if (flag) {
                    val = *reinterpret_cast<const ushort4*>(
                        (const u16*)xin + (size_t)n * 3200 + row * 128 + c4 * 4);
                } else {
                    float4 f = *reinterpret_cast<const float4*>(
                        (const float*)xin + (size_t)n * 3200 + row * 128 + c4 * 4);
                    val.x = f2bf(f.x); val.y = f2bf(f.y);
                    val.z = f2bf(f.z); val.w = f2bf(f.w);
                }
            }
            *reinterpret_cast<ushort4*>(xs_b + swz(row, c4 * 8)) = val;
        }
        for (int i = tid; i < 448; i += 256)          // hs rows 25..31
            ((u32*)(hs_b + 25 * 256))[i] = 0;
    }
    __syncthreads();

    // ---- P1: gate (swapped: A=wsT, B=x row0 on lr==0) + so3lin1 (masked M) ----
    f32x4 gate_v[2];
    {
        #pragma unroll
        for (int nn = 0; nn < 2; ++nn) {
            int cc = nn ? cc1 : cc0;
            f32x4 acc = {0.f, 0.f, 0.f, 0.f};
            #pragma unroll
            for (int ks = 0; ks < 4; ++ks) {
                short8 a = *reinterpret_cast<const short8*>(
                    wsT + cc * 128 + ks * 32 + lq * 8);
                short8 b = zero8;
                if (lr == 0)
                    b = *reinterpret_cast<const short8*>(
                        xs_b + swz(0, ks * 64 + lq * 16));
                acc = MFMA(a, b, acc);
            }
            #pragma unroll
            for (int r = 0; r < 4; ++r) {
                int c = (w * 2 + nn) * 16 + lq * 4 + r;
                gate_v[nn][r] = silu_f(acc[r] + bf2f(bsb[c]));
            }
        }
        const int m0[5] = {0, 1, 4, 9, 16};
        const int ml[5] = {1, 3, 5, 7, 9};
        #pragma unroll
        for (int l = 0; l < 5; ++l) {
            bool valid = lr < ml[l];
            #pragma unroll
            for (int nn = 0; nn < 2; ++nn) {
                int c = (w * 2 + nn) * 16 + lr;
                f32x4 acc = {0.f, 0.f, 0.f, 0.f};
                #pragma unroll
                for (int ks = 0; ks < 4; ++ks) {
                    short8 av = *reinterpret_cast<const short8*>(
                        xs_b + swz(m0[l] + lr, (ks * 32 + lq * 8) * 2));
                    short8 a = valid ? av : zero8;
                    short8 b = *reinterpret_cast<const short8*>(
                        w1T + (l * 128 + c) * 128 + ks * 32 + lq * 8);
                    acc = MFMA(a, b, acc);
                }
                #pragma unroll
                for (int r = 0; r < 4; ++r) {
                    int mm = lq * 4 + r;
                    if (mm < ml[l]) {
                        int i = m0[l] + mm;
                        float v2 = acc[r] + ((i == 0) ? bf2f(b1b[c]) : 0.f);
                        *reinterpret_cast<u16*>(hs_b + swz(i, c * 2)) = f2bf(v2);
                    }
                }
            }
        }
    }
    __syncthreads();

    // ---- P1.5: hw1 = h @ wg1 -> hw1T[d][i] (packed along i) ----
    {
        #pragma unroll
        for (int mt = 0; mt < 2; ++mt) {
            #pragma unroll
            for (int nn = 0; nn < 2; ++nn) {
                int cc = nn ? cc1 : cc0;
                f32x4 acc = {0.f, 0.f, 0.f, 0.f};
                #pragma unroll
                for (int ks = 0; ks < 4; ++ks) {
                    short8 a = *reinterpret_cast<const short8*>(
                        hs_b + swz(mt * 16 + lr, (ks * 32 + lq * 8) * 2));
                    short8 b = *reinterpret_cast<const short8*>(
                        wg1T + cc * 128 + ks * 32 + lq * 8);
                    acc = MFMA(a, b, acc);
                }
                uint2 pk;
                pk.x = f2bf2(acc[0], acc[1]);
                pk.y = f2bf2(acc[2], acc[3]);
                *reinterpret_cast<uint2*>(&hw1T[cc * SW1 + mt * 16 + lq * 4]) = pk;
            }
        }
    }
    __syncthreads();

    // ---- hoisted loop-invariant fragments ----
    short8 bh[2];      // (a') A: hw1T
    short8 bfr[2][4];  // (b)  B: wg2T
    #pragma unroll
    for (int nn = 0; nn < 2; ++nn) {
        int cc = nn ? cc1 : cc0;
        bh[nn] = *reinterpret_cast<const short8*>(&hw1T[cc * SW1 + lq * 8]);
        #pragma unroll
        for (int ks = 0; ks < 4; ++ks)
            bfr[nn][ks] = *reinterpret_cast<const short8*>(
                wg2T + cc * 128 + ks * 32 + lq * 8);
    }

    // ---- P2: 6 chunks of 64 grid rows ----
    f32x4 facc[2][2];  // [nn(c2-tile)][it(i-tile)], rows = c2
    #pragma unroll
    for (int i = 0; i < 2; ++i)
        #pragma unroll
        for (int j = 0; j < 2; ++j) facc[i][j] = f32x4{0.f, 0.f, 0.f, 0.f};

    for (int ch = 0; ch < 6; ++ch) {
        // (a') a1T-compute: A=hw1T frags, B=tg frags -> packed a1R[grow][c]
        #pragma unroll
        for (int mt = 0; mt < 4; ++mt) {
            short8 tgf = *reinterpret_cast<const short8*>(
                tgp + (ch * 64 + mt * 16 + lr) * 32 + lq * 8);
            #pragma unroll
            for (int nn = 0; nn < 2; ++nn) {
                f32x4 acc = MFMA(bh[nn], tgf, f32x4{0.f, 0.f, 0.f, 0.f});
                uint2 pk;
                pk.x = f2bf2(silu_f(acc[0]), silu_f(acc[1]));
                pk.y = f2bf2(silu_f(acc[2]), silu_f(acc[3]));
                *reinterpret_cast<uint2*>(
                    gA_b + swz(mt * 16 + lr, (w * 2 + nn) * 32 + lq * 8)) = pk;
            }
        }
        __syncthreads();

        // (b) a2 = silu(a1 @ wg2): A=a1R row-major, B=wg2T (hoisted) -> gTl[c2][grow]
        #pragma unroll
        for (int mt = 0; mt < 4; ++mt) {
            f32x4 a0 = {0.f, 0.f, 0.f, 0.f}, a1v = {0.f, 0.f, 0.f, 0.f};
            #pragma unroll
            for (int ks = 0; ks < 4; ++ks) {
                short8 af = *reinterpret_cast<const short8*>(
                    gA_b + swz(mt * 16 + lr, ks * 64 + lq * 16));
                a0 = MFMA(af, bfr[0][ks], a0);
                a1v = MFMA(af, bfr[1][ks], a1v);
            }
            uint2 p0, p1;
            p0.x = f2bf2(silu_f(a0[0]), silu_f(a0[1]));
            p0.y = f2bf2(silu_f(a0[2]), silu_f(a0[3]));
            p1.x = f2bf2(silu_f(a1v[0]), silu_f(a1v[1]));
            p1.y = f2bf2(silu_f(a1v[2]), silu_f(a1v[3]));
            *reinterpret_cast<uint2*>(&gTl[cc0 * SGT + mt * 16 + lq * 4]) = p0;
            *reinterpret_cast<uint2*>(&gTl[cc1 * SGT + mt * 16 + lq * 4]) = p1;
        }
        __syncthreads();

        // (e') faccT[c2][i] += A(gTl frags) @ B(fgT frags)
        #pragma unroll
        for (int it = 0; it < 2; ++it) {
            #pragma unroll
            for (int ks = 0; ks < 2; ++ks) {
                short8 bf_ = *reinterpret_cast<const short8*>(
                    fgT + (it * 16 + lr) * 384 + ch * 64 + ks * 32 + lq * 8);
                #pragma unroll
                for (int nn = 0; nn < 2; ++nn) {
                    short8 ag = *reinterpret_cast<const short8*>(
                        &gTl[(nn ? cc1 : cc0) * SGT + ks * 32 + lq * 8]);
                    facc[nn][it] = MFMA(ag, bf_, facc[nn][it]);
                }
            }
        }
        // no barrier: next (a') writes only a1R; its barrier also protects gTl.
    }

    // ---- P3a: pack faccT -> h2p[i][c2] row-major (xs area) ----
    #pragma unroll
    for (int nn = 0; nn < 2; ++nn)
        #pragma unroll
        for (int it = 0; it < 2; ++it) {
            uint2 pk;
            pk.x = f2bf2(facc[nn][it][0], facc[nn][it][1]);
            pk.y = f2bf2(facc[nn][it][2], facc[nn][it][3]);
            *reinterpret_cast<uint2*>(
                xs_b + swz(it * 16 + lr, (w * 2 + nn) * 32 + lq * 8)) = pk;
        }
    __syncthreads();

    // ---- P3b: h2T = wg3T(A) @ h2p(B); merge gate at i==0; pack h2R[i][c3] ----
    #pragma unroll
    for (int it = 0; it < 2; ++it) {
        #pragma unroll
        for (int nn = 0; nn < 2; ++nn) {
            int cc = nn ? cc1 : cc0;
            f32x4 acc = {0.f, 0.f, 0.f, 0.f};
            #pragma unroll
            for (int ks = 0; ks < 4; ++ks) {
                short8 a = *reinterpret_cast<const short8*>(
                    wg3T + cc * 128 + ks * 32 + lq * 8);
                short8 b = *reinterpret_cast<const short8*>(
                    xs_b + swz(it * 16 + lr, ks * 64 + lq * 16));
                acc = MFMA(a, b, acc);
            }
            if (it == 0 && lr == 0) acc = gate_v[nn];
            uint2 pk;
            pk.x = f2bf2(acc[0], acc[1]);
            pk.y = f2bf2(acc[2], acc[3]);
            *reinterpret_cast<uint2*>(
                hs_b + swz(it * 16 + lr, (w * 2 + nn) * 32 + lq * 8)) = pk;
        }
    }
    __syncthreads();

    // ---- P3c: out = so3lin2(h2R) + b2 on i==0 ----
    {
        const int m0[5] = {0, 1, 4, 9, 16};
        const int ml[5] = {1, 3, 5, 7, 9};
        #pragma unroll
        for (int l = 0; l < 5; ++l) {
            bool valid = lr < ml[l];
            #pragma unroll
            for (int nn = 0; nn < 2; ++nn) {
                int c = (w * 2 + nn) * 16 + lr;
                f32x4 acc = {0.f, 0.f, 0.f, 0.f};
                #pragma unroll
                for (int ks = 0; ks < 4; ++ks) {
                    short8 av = *reinterpret_cast<const short8*>(
                        hs_b + swz(m0[l] + lr, (ks * 32 + lq * 8) * 2));
                    short8 a = valid ? av : zero8;
                    short8 b = *reinterpret_cast<const short8*>(
                        w2T + (l * 128 + c) * 128 + ks * 32 + lq * 8);
                    acc = MFMA(a, b, acc);
                }
                #pragma unroll
                for (int r = 0; r < 4; ++r) {
                    int mm = lq * 4 + r;
                    if (mm < ml[l]) {
                        int i = m0[l] + mm;
                        float v2 = acc[r] + ((i == 0) ? bf2f(b2b[c]) : 0.f);
                        size_t o = (size_t)n * 3200 + i * 128 + c;
                        if (flag) ((u16*)outp)[o] = f2bf(v2);
                        else      ((float*)outp)[o] = v2;
                    }
                }
            }
        }
    }
}

extern "C" void kernel_launch(void* const* d_in, const int* in_sizes, int n_in,
                              void* d_out, int out_size, void* d_ws, size_t ws_size,
                              hipStream_t stream) {
    const void* x   = d_in[0];
    const void* w1  = d_in[1];
    const void* b1  = d_in[2];
    const void* wsm = d_in[3];
    const void* bs  = d_in[4];
    const void* wg1 = d_in[5];
    const void* wg2 = d_in[6];
    const void* wg3 = d_in[7];
    const void* w2  = d_in[8];
    const void* b2  = d_in[9];
    const void* tg  = d_in[10];
    const void* fg  = d_in[11];
    u16* wsp = (u16*)d_ws;
    u32* flagp = (u32*)(wsp + OFF_FLAG);

    detect_kernel<<<1, 64, 0, stream>>>(x, flagp);
    prep_kernel<<<(PREP_TOTAL + 255) / 256, 256, 0, stream>>>(
        w1, wg1, wg2, wg3, w2, tg, fg, wsm, b1, bs, b2, wsp, flagp);
    ffn_kernel<<<2048, 256, 0, stream>>>(x, wsp, d_out);
}

// Round 7
// 264.102 us; speedup vs baseline: 1.6738x; 1.0163x over previous
//
#include <hip/hip_runtime.h>
#include <hip/hip_bf16.h>

typedef unsigned short u16;
typedef unsigned int u32;
typedef __attribute__((ext_vector_type(8))) short short8;
typedef __attribute__((ext_vector_type(8))) __bf16 bf16x8;
typedef __attribute__((ext_vector_type(4))) float f32x4;

// ---------- helpers ----------
__device__ __forceinline__ float bf2f(u16 u) {
    union { float f; unsigned int i; } v; v.i = ((unsigned int)u) << 16; return v.f;
}
// manual RNE f32->bf16 (values finite; no NaN path needed)
__device__ __forceinline__ u16 f2bf(float f) {
    u32 b = __builtin_bit_cast(u32, f);
    b += 0x7FFFu + ((b >> 16) & 1u);
    return (u16)(b >> 16);
}
// pack two f32 -> two bf16 in one u32 (lo=f0, hi=f1)
__device__ __forceinline__ u32 f2bf2(float f0, float f1) {
    u32 b0 = __builtin_bit_cast(u32, f0);
    u32 b1 = __builtin_bit_cast(u32, f1);
    b0 += 0x7FFFu + ((b0 >> 16) & 1u);
    b1 += 0x7FFFu + ((b1 >> 16) & 1u);
    return (b0 >> 16) | (b1 & 0xFFFF0000u);
}
// fast silu: x * rcp(1+exp(-x))
__device__ __forceinline__ float silu_f(float v) {
    return v * __builtin_amdgcn_rcpf(1.0f + __expf(-v));
}
// XOR swizzle for row-major [rows][128] bf16 tiles (256B rows).
__device__ __forceinline__ unsigned swz(unsigned row, unsigned colbyte) {
    return row * 256u + (colbyte ^ ((row & 7u) << 4));
}
__device__ __forceinline__ f32x4 MFMA(short8 a, short8 b, f32x4 c) {
    return __builtin_amdgcn_mfma_f32_16x16x32_bf16(
        __builtin_bit_cast(bf16x8, a), __builtin_bit_cast(bf16x8, b), c, 0, 0, 0);
}

#define SW1 40   // hw1T row stride (u16)
#define SGT 40   // gTl  row stride (u16): 32 rows + pad (80B rows, 16B-aligned frags)

// ---------- workspace layout (u16 element offsets) ----------
#define OFF_W1T 0        // [5][128][128] w1T[l][cout][cin]
#define OFF_W2T 81920    // [5][128][128]
#define OFF_WGT 163840   // [3][128][128] wgT[j][cout][cin]
#define OFF_TGP 212992   // [384][32]  zero-padded to_grid
#define OFF_FGT 225280   // [32][384]  zero-padded from_grid, transposed
#define OFF_WSB 237568   // [128][128] wsT[cout][cin] (gating matrix, transposed)
#define OFF_B1B 253952   // [128]
#define OFF_BSB 254080   // [128]
#define OFF_B2B 254208   // [128]
#define PREP_TOTAL 254336
#define OFF_FLAG 254336  // u32 flag

// ---- dtype detector: 1 = device buffers are bf16, 0 = float32 ----
__global__ void detect_kernel(const void* __restrict__ x, u32* __restrict__ flagp) {
    int tid = threadIdx.x;  // 64 threads
    const u16* p = (const u16*)x;
    int cnt = 0;
    #pragma unroll
    for (int j = 0; j < 8; ++j) {
        float v = fabsf(bf2f(p[2 * (tid * 8 + j)]));
        if (v >= 1e-4f && v <= 100.0f) ++cnt;
    }
    #pragma unroll
    for (int d = 32; d; d >>= 1) cnt += __shfl_down(cnt, d);
    if (tid == 0) *flagp = (cnt >= 256) ? 1u : 0u;
}

__global__ void prep_kernel(const void* __restrict__ w1, const void* __restrict__ wg1,
                            const void* __restrict__ wg2, const void* __restrict__ wg3,
                            const void* __restrict__ w2, const void* __restrict__ tg,
                            const void* __restrict__ fg, const void* __restrict__ wsm,
                            const void* __restrict__ b1, const void* __restrict__ bs,
                            const void* __restrict__ b2,
                            u16* __restrict__ wsp, const u32* __restrict__ flagp) {
    const int flag = (int)*flagp;
    int idx = blockIdx.x * 256 + threadIdx.x;
    if (idx >= PREP_TOTAL) return;
    auto ld = [&](const void* p, int s) -> u16 {
        return flag ? ((const u16*)p)[s] : f2bf(((const float*)p)[s]);
    };
    if (idx < OFF_W2T) {
        int l = idx >> 14, c = (idx >> 7) & 127, k = idx & 127;
        wsp[idx] = ld(w1, (l << 14) + (k << 7) + c);
    } else if (idx < OFF_WGT) {
        int j = idx - OFF_W2T;
        int l = j >> 14, c = (j >> 7) & 127, k = j & 127;
        wsp[idx] = ld(w2, (l << 14) + (k << 7) + c);
    } else if (idx < OFF_TGP) {
        int j = idx - OFF_WGT;
        int m = j >> 14, c = (j >> 7) & 127, k = j & 127;
        const void* w = (m == 0) ? wg1 : (m == 1) ? wg2 : wg3;
        wsp[idx] = ld(w, (k << 7) + c);
    } else if (idx < OFF_FGT) {
        int j = idx - OFF_TGP;
        int r = j >> 5, i = j & 31;
        wsp[idx] = (r < 324 && i < 25) ? ld(tg, r * 25 + i) : (u16)0;
    } else if (idx < OFF_WSB) {
        int j = idx - OFF_FGT;
        int i = j / 384, r = j % 384;
        wsp[idx] = (i < 25 && r < 324) ? ld(fg, r * 25 + i) : (u16)0;
    } else if (idx < OFF_B1B) {
        int j = idx - OFF_WSB;     // j = c*128 + k ; wsT[c][k] = ws[k][c]
        wsp[idx] = ld(wsm, ((j & 127) << 7) + (j >> 7));
    } else if (idx < OFF_BSB) {
        wsp[idx] = ld(b1, idx - OFF_B1B);
    } else if (idx < OFF_B2B) {
        wsp[idx] = ld(bs, idx - OFF_BSB);
    } else {
        wsp[idx] = ld(b2, idx - OFF_B2B);
    }
}

// Fused pipeline; chunk loop is a 3-stage software pipeline over 12 chunks
// of 32 grid rows: interval k = { e'(k) ; b(k+1) ; a'(k+2) } + one barrier.
// Double-buffered a1R (in ldsA) and gTl give each interval 3 independent
// streams -> latency hiding without extra barriers.
__global__ __launch_bounds__(256, 3) void ffn_kernel(
    const void* __restrict__ xin, const u16* __restrict__ wsp,
    void* __restrict__ outp) {
    const u16* w1T  = wsp + OFF_W1T;
    const u16* w2T  = wsp + OFF_W2T;
    const u16* wg1T = wsp + OFF_WGT;
    const u16* wg2T = wsp + OFF_WGT + 16384;
    const u16* wg3T = wsp + OFF_WGT + 32768;
    const u16* tgp  = wsp + OFF_TGP;
    const u16* fgT  = wsp + OFF_FGT;
    const u16* wsT  = wsp + OFF_WSB;
    const u16* b1b  = wsp + OFF_B1B;
    const u16* bsb  = wsp + OFF_BSB;
    const u16* b2b  = wsp + OFF_B2B;
    const int flag = (int)*(const u32*)(wsp + OFF_FLAG);

    __shared__ u16 ldsA[64 * 128];     // P1: xs+hs; chunks: a1R[2][32][128]; P3: h2p+h2R
    __shared__ u16 hw1T[128 * SW1];    // hw1 transposed [d][i]
    __shared__ u16 gTl[2][128 * SGT];  // a2 transposed [c2][grow], double-buffered

    const int tid = threadIdx.x;
    const int w = tid >> 6;
    const int lane = tid & 63;
    const int lq = lane >> 4;
    const int lr = lane & 15;
    const int n = blockIdx.x;

    char* gA_b = reinterpret_cast<char*>(ldsA);   // rows 0..63
    char* xs_b = gA_b;                            // rows 0..31
    char* hs_b = gA_b + 32 * 256;                 // rows 32..63
    const short8 zero8 = {0, 0, 0, 0, 0, 0, 0, 0};
    const int cc0 = (w * 2) * 16 + lr, cc1 = (w * 2 + 1) * 16 + lr;

    // ---- P0: stage x[n] (row-major swizzled; rows 25..31 zero); zero hs tail ----
    {
        #pragma unroll
        for (int v = 0; v < 4; ++v) {
            int idx = tid + v * 256;
            int row = idx >> 5, c4 = idx & 31;
            ushort4 val = make_ushort4(0, 0, 0, 0);
            if (row < 25) {
                if (flag) {
                    val = *reinterpret_cast<const ushort4*>(
                        (const u16*)xin + (size_t)n * 3200 + row * 128 + c4 * 4);
                } else {
                    float4 f = *reinterpret_cast<const float4*>(
                        (const float*)xin + (size_t)n * 3200 + row * 128 + c4 * 4);
                    val.x = f2bf(f.x); val.y = f2bf(f.y);
                    val.z = f2bf(f.z); val.w = f2bf(f.w);
                }
            }
            *reinterpret_cast<ushort4*>(xs_b + swz(row, c4 * 8)) = val;
        }
        for (int i = tid; i < 448; i += 256)          // hs rows 25..31
            ((u32*)(hs_b + 25 * 256))[i] = 0;
    }
    __syncthreads();

    // ---- P1: gate (A=wsT, B=x row0 on lr==0) + so3lin1 (masked M) ----
    f32x4 gate_v[2];
    {
        #pragma unroll
        for (int nn = 0; nn < 2; ++nn) {
            int cc = nn ? cc1 : cc0;
            f32x4 acc = {0.f, 0.f, 0.f, 0.f};
            #pragma unroll
            for (int ks = 0; ks < 4; ++ks) {
                short8 a = *reinterpret_cast<const short8*>(
                    wsT + cc * 128 + ks * 32 + lq * 8);
                short8 b = zero8;
                if (lr == 0)
                    b = *reinterpret_cast<const short8*>(
                        xs_b + swz(0, ks * 64 + lq * 16));
                acc = MFMA(a, b, acc);
            }
            #pragma unroll
            for (int r = 0; r < 4; ++r) {
                int c = (w * 2 + nn) * 16 + lq * 4 + r;
                gate_v[nn][r] = silu_f(acc[r] + bf2f(bsb[c]));
            }
        }
        const int m0[5] = {0, 1, 4, 9, 16};
        const int ml[5] = {1, 3, 5, 7, 9};
        #pragma unroll
        for (int l = 0; l < 5; ++l) {
            bool valid = lr < ml[l];
            #pragma unroll
            for (int nn = 0; nn < 2; ++nn) {
                int c = (w * 2 + nn) * 16 + lr;
                f32x4 acc = {0.f, 0.f, 0.f, 0.f};
                #pragma unroll
                for (int ks = 0; ks < 4; ++ks) {
                    short8 av = *reinterpret_cast<const short8*>(
                        xs_b + swz(m0[l] + lr, (ks * 32 + lq * 8) * 2));
                    short8 a = valid ? av : zero8;
                    short8 b = *reinterpret_cast<const short8*>(
                        w1T + (l * 128 + c) * 128 + ks * 32 + lq * 8);
                    acc = MFMA(a, b, acc);
                }
                #pragma unroll
                for (int r = 0; r < 4; ++r) {
                    int mm = lq * 4 + r;
                    if (mm < ml[l]) {
                        int i = m0[l] + mm;
                        float v2 = acc[r] + ((i == 0) ? bf2f(b1b[c]) : 0.f);
                        *reinterpret_cast<u16*>(hs_b + swz(i, c * 2)) = f2bf(v2);
                    }
                }
            }
        }
    }
    __syncthreads();

    // ---- P1.5: hw1 = h @ wg1 -> hw1T[d][i] (packed along i) ----
    {
        #pragma unroll
        for (int mt = 0; mt < 2; ++mt) {
            #pragma unroll
            for (int nn = 0; nn < 2; ++nn) {
                int cc = nn ? cc1 : cc0;
                f32x4 acc = {0.f, 0.f, 0.f, 0.f};
                #pragma unroll
                for (int ks = 0; ks < 4; ++ks) {
                    short8 a = *reinterpret_cast<const short8*>(
                        hs_b + swz(mt * 16 + lr, (ks * 32 + lq * 8) * 2));
                    short8 b = *reinterpret_cast<const short8*>(
                        wg1T + cc * 128 + ks * 32 + lq * 8);
                    acc = MFMA(a, b, acc);
                }
                uint2 pk;
                pk.x = f2bf2(acc[0], acc[1]);
                pk.y = f2bf2(acc[2], acc[3]);
                *reinterpret_cast<uint2*>(&hw1T[cc * SW1 + mt * 16 + lq * 4]) = pk;
            }
        }
    }
    __syncthreads();

    // ---- hoisted loop-invariant fragments ----
    short8 bh[2];      // (a') A: hw1T
    short8 bfr[2][4];  // (b)  B: wg2T
    #pragma unroll
    for (int nn = 0; nn < 2; ++nn) {
        int cc = nn ? cc1 : cc0;
        bh[nn] = *reinterpret_cast<const short8*>(&hw1T[cc * SW1 + lq * 8]);
        #pragma unroll
        for (int ks = 0; ks < 4; ++ks)
            bfr[nn][ks] = *reinterpret_cast<const short8*>(
                wg2T + cc * 128 + ks * 32 + lq * 8);
    }

    f32x4 facc[2][2];  // [nn(c2-tile)][it(i-tile)]
    #pragma unroll
    for (int i = 0; i < 2; ++i)
        #pragma unroll
        for (int j = 0; j < 2; ++j) facc[i][j] = f32x4{0.f, 0.f, 0.f, 0.f};

    // ---- P2: 12 chunks of 32 grid rows, 3-stage software pipeline ----
    auto phase_a = [&](int ch) {   // a1 = silu(tg_ch @ hw1) -> a1R[ch&1]
        char* dst = gA_b + (ch & 1) * 8192;
        #pragma unroll
        for (int mt = 0; mt < 2; ++mt) {
            short8 tgf = *reinterpret_cast<const short8*>(
                tgp + (ch * 32 + mt * 16 + lr) * 32 + lq * 8);
            #pragma unroll
            for (int nn = 0; nn < 2; ++nn) {
                f32x4 acc = MFMA(bh[nn], tgf, f32x4{0.f, 0.f, 0.f, 0.f});
                uint2 pk;
                pk.x = f2bf2(silu_f(acc[0]), silu_f(acc[1]));
                pk.y = f2bf2(silu_f(acc[2]), silu_f(acc[3]));
                *reinterpret_cast<uint2*>(
                    dst + swz(mt * 16 + lr, (w * 2 + nn) * 32 + lq * 8)) = pk;
            }
        }
    };
    auto phase_b = [&](int ch) {   // a2 = silu(a1 @ wg2) -> gTl[ch&1][c2][grow]
        const char* src = gA_b + (ch & 1) * 8192;
        u16* gdst = &gTl[ch & 1][0];
        #pragma unroll
        for (int mt = 0; mt < 2; ++mt) {
            f32x4 a0 = {0.f, 0.f, 0.f, 0.f}, a1v = {0.f, 0.f, 0.f, 0.f};
            #pragma unroll
            for (int ks = 0; ks < 4; ++ks) {
                short8 af = *reinterpret_cast<const short8*>(
                    src + swz(mt * 16 + lr, ks * 64 + lq * 16));
                a0 = MFMA(af, bfr[0][ks], a0);
                a1v = MFMA(af, bfr[1][ks], a1v);
            }
            uint2 p0, p1;
            p0.x = f2bf2(silu_f(a0[0]), silu_f(a0[1]));
            p0.y = f2bf2(silu_f(a0[2]), silu_f(a0[3]));
            p1.x = f2bf2(silu_f(a1v[0]), silu_f(a1v[1]));
            p1.y = f2bf2(silu_f(a1v[2]), silu_f(a1v[3]));
            *reinterpret_cast<uint2*>(&gdst[cc0 * SGT + mt * 16 + lq * 4]) = p0;
            *reinterpret_cast<uint2*>(&gdst[cc1 * SGT + mt * 16 + lq * 4]) = p1;
        }
    };
    auto phase_e = [&](int ch) {   // faccT[c2][i] += a2T @ fgT_ch
        const u16* gsrc = &gTl[ch & 1][0];
        #pragma unroll
        for (int it = 0; it < 2; ++it) {
            short8 bf_ = *reinterpret_cast<const short8*>(
                fgT + (it * 16 + lr) * 384 + ch * 32 + lq * 8);
            #pragma unroll
            for (int nn = 0; nn < 2; ++nn) {
                short8 ag = *reinterpret_cast<const short8*>(
                    &gsrc[(nn ? cc1 : cc0) * SGT + lq * 8]);
                facc[nn][it] = MFMA(ag, bf_, facc[nn][it]);
            }
        }
    };

    phase_a(0);
    __syncthreads();
    phase_b(0);
    phase_a(1);
    __syncthreads();
    #pragma unroll 2
    for (int k = 0; k <= 9; ++k) {
        phase_e(k);
        phase_b(k + 1);
        phase_a(k + 2);
        __syncthreads();
    }
    phase_e(10);
    phase_b(11);
    __syncthreads();
    phase_e(11);

    // ---- P3a: pack faccT -> h2p[i][c2] row-major (xs area) ----
    #pragma unroll
    for (int nn = 0; nn < 2; ++nn)
        #pragma unroll
        for (int it = 0; it < 2; ++it) {
            uint2 pk;
            pk.x = f2bf2(facc[nn][it][0], facc[nn][it][1]);
            pk.y = f2bf2(facc[nn][it][2], facc[nn][it][3]);
            *reinterpret_cast<uint2*>(
                xs_b + swz(it * 16 + lr, (w * 2 + nn) * 32 + lq * 8)) = pk;
        }
    __syncthreads();

    // ---- P3b: h2 = wg3T(A) @ h2p(B); merge gate at i==0; pack h2R[i][c3] ----
    #pragma unroll
    for (int it = 0; it < 2; ++it) {
        #pragma unroll
        for (int nn = 0; nn < 2; ++nn) {
            int cc = nn ? cc1 : cc0;
            f32x4 acc = {0.f, 0.f, 0.f, 0.f};
            #pragma unroll
            for (int ks = 0; ks < 4; ++ks) {
                short8 a = *reinterpret_cast<const short8*>(
                    wg3T + cc * 128 + ks * 32 + lq * 8);
                short8 b = *reinterpret_cast<const short8*>(
                    xs_b + swz(it * 16 + lr, ks * 64 + lq * 16));
                acc = MFMA(a, b, acc);
            }
            if (it == 0 && lr == 0) acc = gate_v[nn];
            uint2 pk;
            pk.x = f2bf2(acc[0], acc[1]);
            pk.y = f2bf2(acc[2], acc[3]);
            *reinterpret_cast<uint2*>(
                hs_b + swz(it * 16 + lr, (w * 2 + nn) * 32 + lq * 8)) = pk;
        }
    }
    __syncthreads();

    // ---- P3c: out = so3lin2(h2R) + b2 on i==0 ----
    {
        const int m0[5] = {0, 1, 4, 9, 16};
        const int ml[5] = {1, 3, 5, 7, 9};
        #pragma unroll
        for (int l = 0; l < 5; ++l) {
            bool valid = lr < ml[l];
            #pragma unroll
            for (int nn = 0; nn < 2; ++nn) {
                int c = (w * 2 + nn) * 16 + lr;
                f32x4 acc = {0.f, 0.f, 0.f, 0.f};
                #pragma unroll
                for (int ks = 0; ks < 4; ++ks) {
                    short8 av = *reinterpret_cast<const short8*>(
                        hs_b + swz(m0[l] + lr, (ks * 32 + lq * 8) * 2));
                    short8 a = valid ? av : zero8;
                    short8 b = *reinterpret_cast<const short8*>(
                        w2T + (l * 128 + c) * 128 + ks * 32 + lq * 8);
                    acc = MFMA(a, b, acc);
                }
                #pragma unroll
                for (int r = 0; r < 4; ++r) {
                    int mm = lq * 4 + r;
                    if (mm < ml[l]) {
                        int i = m0[l] + mm;
                        float v2 = acc[r] + ((i == 0) ? bf2f(b2b[c]) : 0.f);
                        size_t o = (size_t)n * 3200 + i * 128 + c;
                        if (flag) ((u16*)outp)[o] = f2bf(v2);
                        else      ((float*)outp)[o] = v2;
                    }
                }
            }
        }
    }
}

extern "C" void kernel_launch(void* const* d_in, const int* in_sizes, int n_in,
                              void* d_out, int out_size, void* d_ws, size_t ws_size,
                              hipStream_t stream) {
    const void* x   = d_in[0];
    const void* w1  = d_in[1];
    const void* b1  = d_in[2];
    const void* wsm = d_in[3];
    const void* bs  = d_in[4];
    const void* wg1 = d_in[5];
    const void* wg2 = d_in[6];
    const void* wg3 = d_in[7];
    const void* w2  = d_in[8];
    const void* b2  = d_in[9];
    const void* tg  = d_in[10];
    const void* fg  = d_in[11];
    u16* wsp = (u16*)d_ws;
    u32* flagp = (u32*)(wsp + OFF_FLAG);

    detect_kernel<<<1, 64, 0, stream>>>(x, flagp);
    prep_kernel<<<(PREP_TOTAL + 255) / 256, 256, 0, stream>>>(
        w1, wg1, wg2, wg3, w2, tg, fg, wsm, b1, bs, b2, wsp, flagp);
    ffn_kernel<<<2048, 256, 0, stream>>>(x, wsp, d_out);
}

// Round 10
// 253.058 us; speedup vs baseline: 1.7468x; 1.0436x over previous
//
#include <hip/hip_runtime.h>
#include <hip/hip_bf16.h>

typedef unsigned short u16;
typedef unsigned int u32;
typedef __attribute__((ext_vector_type(8))) short short8;
typedef __attribute__((ext_vector_type(8))) __bf16 bf16x8;
typedef __attribute__((ext_vector_type(2))) __bf16 bf16x2;
typedef __attribute__((ext_vector_type(4))) float f32x4;

// ---------- helpers ----------
__device__ __forceinline__ float bf2f(u16 u) {
    union { float f; unsigned int i; } v; v.i = ((unsigned int)u) << 16; return v.f;
}
// native f32->bf16 (gfx950 v_cvt_pk_bf16_f32, RNE) — do NOT hand-roll (m240)
__device__ __forceinline__ u16 f2bf(float f) {
    __bf16 h = (__bf16)f;
    return __builtin_bit_cast(u16, h);
}
__device__ __forceinline__ u32 f2bf2(float f0, float f1) {
    bf16x2 v; v[0] = (__bf16)f0; v[1] = (__bf16)f1;
    return __builtin_bit_cast(u32, v);
}
// fast silu: x * rcp(1+exp(-x))
__device__ __forceinline__ float silu_f(float v) {
    return v * __builtin_amdgcn_rcpf(1.0f + __expf(-v));
}
// XOR swizzle for row-major [rows][128] bf16 tiles (256B rows).
__device__ __forceinline__ unsigned swz(unsigned row, unsigned colbyte) {
    return row * 256u + (colbyte ^ ((row & 7u) << 4));
}
__device__ __forceinline__ f32x4 MFMA(short8 a, short8 b, f32x4 c) {
    return __builtin_amdgcn_mfma_f32_16x16x32_bf16(
        __builtin_bit_cast(bf16x8, a), __builtin_bit_cast(bf16x8, b), c, 0, 0, 0);
}

#define SW1 40   // hw1T row stride (u16)
#define SGT 40   // gTl  row stride (u16)

// ---------- workspace layout (u16 element offsets) ----------
#define OFF_W1T 0        // [5][128][128] w1T[l][cout][cin]
#define OFF_W2T 81920    // [5][128][128]
#define OFF_WGT 163840   // [3][128][128] wgT[j][cout][cin]
#define OFF_TGP 212992   // [384][32]  zero-padded to_grid
#define OFF_FGT 225280   // [32][384]  zero-padded from_grid, transposed
#define OFF_WSB 237568   // [128][128] wsT[cout][cin] (gating matrix, transposed)
#define OFF_B1B 253952   // [128]
#define OFF_BSB 254080   // [128]
#define OFF_B2B 254208   // [128]
#define PREP_TOTAL 254336
#define OFF_FLAG 254336  // u32 flag

// ---- dtype detector: 1 = device buffers are bf16, 0 = float32 ----
__global__ void detect_kernel(const void* __restrict__ x, u32* __restrict__ flagp) {
    int tid = threadIdx.x;  // 64 threads
    const u16* p = (const u16*)x;
    int cnt = 0;
    #pragma unroll
    for (int j = 0; j < 8; ++j) {
        float v = fabsf(bf2f(p[2 * (tid * 8 + j)]));
        if (v >= 1e-4f && v <= 100.0f) ++cnt;
    }
    #pragma unroll
    for (int d = 32; d; d >>= 1) cnt += __shfl_down(cnt, d);
    if (tid == 0) *flagp = (cnt >= 256) ? 1u : 0u;
}

__global__ void prep_kernel(const void* __restrict__ w1, const void* __restrict__ wg1,
                            const void* __restrict__ wg2, const void* __restrict__ wg3,
                            const void* __restrict__ w2, const void* __restrict__ tg,
                            const void* __restrict__ fg, const void* __restrict__ wsm,
                            const void* __restrict__ b1, const void* __restrict__ bs,
                            const void* __restrict__ b2,
                            u16* __restrict__ wsp, const u32* __restrict__ flagp) {
    const int flag = (int)*flagp;
    int idx = blockIdx.x * 256 + threadIdx.x;
    if (idx >= PREP_TOTAL) return;
    auto ld = [&](const void* p, int s) -> u16 {
        return flag ? ((const u16*)p)[s] : f2bf(((const float*)p)[s]);
    };
    if (idx < OFF_W2T) {
        int l = idx >> 14, c = (idx >> 7) & 127, k = idx & 127;
        wsp[idx] = ld(w1, (l << 14) + (k << 7) + c);
    } else if (idx < OFF_WGT) {
        int j = idx - OFF_W2T;
        int l = j >> 14, c = (j >> 7) & 127, k = j & 127;
        wsp[idx] = ld(w2, (l << 14) + (k << 7) + c);
    } else if (idx < OFF_TGP) {
        int j = idx - OFF_WGT;
        int m = j >> 14, c = (j >> 7) & 127, k = j & 127;
        const void* w = (m == 0) ? wg1 : (m == 1) ? wg2 : wg3;
        wsp[idx] = ld(w, (k << 7) + c);
    } else if (idx < OFF_FGT) {
        int j = idx - OFF_TGP;
        int r = j >> 5, i = j & 31;
        wsp[idx] = (r < 324 && i < 25) ? ld(tg, r * 25 + i) : (u16)0;
    } else if (idx < OFF_WSB) {
        int j = idx - OFF_FGT;
        int i = j / 384, r = j % 384;
        wsp[idx] = (i < 25 && r < 324) ? ld(fg, r * 25 + i) : (u16)0;
    } else if (idx < OFF_B1B) {
        int j = idx - OFF_WSB;     // j = c*128 + k ; wsT[c][k] = ws[k][c]
        wsp[idx] = ld(wsm, ((j & 127) << 7) + (j >> 7));
    } else if (idx < OFF_BSB) {
        wsp[idx] = ld(b1, idx - OFF_B1B);
    } else if (idx < OFF_B2B) {
        wsp[idx] = ld(bs, idx - OFF_BSB);
    } else {
        wsp[idx] = ld(b2, idx - OFF_B2B);
    }
}

// Fused pipeline. 12 chunks of 32 grid rows; a1R double-buffered (inside
// ldsA), gTl single-buffered. Intervals: {e(k) || a(k+2)} BAR {b(k+1)} BAR.
// LDS 36 KB -> 4 blocks/CU (16 waves/CU); grid 2048 = exactly 2 rounds.
__global__ __launch_bounds__(256, 4) void ffn_kernel(
    const void* __restrict__ xin, const u16* __restrict__ wsp,
    void* __restrict__ outp) {
    const u16* w1T  = wsp + OFF_W1T;
    const u16* w2T  = wsp + OFF_W2T;
    const u16* wg1T = wsp + OFF_WGT;
    const u16* wg2T = wsp + OFF_WGT + 16384;
    const u16* wg3T = wsp + OFF_WGT + 32768;
    const u16* tgp  = wsp + OFF_TGP;
    const u16* fgT  = wsp + OFF_FGT;
    const u16* wsT  = wsp + OFF_WSB;
    const u16* b1b  = wsp + OFF_B1B;
    const u16* bsb  = wsp + OFF_BSB;
    const u16* b2b  = wsp + OFF_B2B;
    const int flag = (int)*(const u32*)(wsp + OFF_FLAG);

    __shared__ u16 ldsA[64 * 128];   // P1: xs+hs; chunks: a1R[2][32][128]; P3: h2p+h2R
    __shared__ u16 hw1T[128 * SW1];  // hw1 transposed [d][i]
    __shared__ u16 gTl[128 * SGT];   // a2 transposed [c2][grow], single buffer

    const int tid = threadIdx.x;
    const int w = tid >> 6;
    const int lane = tid & 63;
    const int lq = lane >> 4;
    const int lr = lane & 15;
    const int n = blockIdx.x;

    char* gA_b = reinterpret_cast<char*>(ldsA);   // rows 0..63
    char* xs_b = gA_b;                            // rows 0..31
    char* hs_b = gA_b + 32 * 256;                 // rows 32..63
    const short8 zero8 = {0, 0, 0, 0, 0, 0, 0, 0};
    const int cc0 = (w * 2) * 16 + lr, cc1 = (w * 2 + 1) * 16 + lr;

    // ---- P0: stage x[n] (row-major swizzled; rows 25..31 zero); zero hs tail ----
    {
        #pragma unroll
        for (int v = 0; v < 4; ++v) {
            int idx = tid + v * 256;
            int row = idx >> 5, c4 = idx & 31;
            ushort4 val = make_ushort4(0, 0, 0, 0);
            if (row < 25) {
                if (flag) {
                    val = *reinterpret_cast<const ushort4*>(
                        (const u16*)xin + (size_t)n * 3200 + row * 128 + c4 * 4);
                } else {
                    float4 f = *reinterpret_cast<const float4*>(
                        (const float*)xin + (size_t)n * 3200 + row * 128 + c4 * 4);
                    val.x = f2bf(f.x); val.y = f2bf(f.y);
                    val.z = f2bf(f.z); val.w = f2bf(f.w);
                }
            }
            *reinterpret_cast<ushort4*>(xs_b + swz(row, c4 * 8)) = val;
        }
        for (int i = tid; i < 448; i += 256)          // hs rows 25..31
            ((u32*)(hs_b + 25 * 256))[i] = 0;
    }
    __syncthreads();

    // ---- P1: gate (A=wsT, B=x row0 on lr==0) + so3lin1 (masked M) ----
    f32x4 gate_v[2];
    {
        #pragma unroll
        for (int nn = 0; nn < 2; ++nn) {
            int cc = nn ? cc1 : cc0;
            f32x4 acc = {0.f, 0.f, 0.f, 0.f};
            #pragma unroll
            for (int ks = 0; ks < 4; ++ks) {
                short8 a = *reinterpret_cast<const short8*>(
                    wsT + cc * 128 + ks * 32 + lq * 8);
                short8 b = zero8;
                if (lr == 0)
                    b = *reinterpret_cast<const short8*>(
                        xs_b + swz(0, ks * 64 + lq * 16));
                acc = MFMA(a, b, acc);
            }
            #pragma unroll
            for (int r = 0; r < 4; ++r) {
                int c = (w * 2 + nn) * 16 + lq * 4 + r;
                gate_v[nn][r] = silu_f(acc[r] + bf2f(bsb[c]));
            }
        }
        const int m0[5] = {0, 1, 4, 9, 16};
        const int ml[5] = {1, 3, 5, 7, 9};
        #pragma unroll
        for (int l = 0; l < 5; ++l) {
            bool valid = lr < ml[l];
            #pragma unroll
            for (int nn = 0; nn < 2; ++nn) {
                int c = (w * 2 + nn) * 16 + lr;
                f32x4 acc = {0.f, 0.f, 0.f, 0.f};
                #pragma unroll
                for (int ks = 0; ks < 4; ++ks) {
                    short8 av = *reinterpret_cast<const short8*>(
                        xs_b + swz(m0[l] + lr, (ks * 32 + lq * 8) * 2));
                    short8 a = valid ? av : zero8;
                    short8 b = *reinterpret_cast<const short8*>(
                        w1T + (l * 128 + c) * 128 + ks * 32 + lq * 8);
                    acc = MFMA(a, b, acc);
                }
                #pragma unroll
                for (int r = 0; r < 4; ++r) {
                    int mm = lq * 4 + r;
                    if (mm < ml[l]) {
                        int i = m0[l] + mm;
                        float v2 = acc[r] + ((i == 0) ? bf2f(b1b[c]) : 0.f);
                        *reinterpret_cast<u16*>(hs_b + swz(i, c * 2)) = f2bf(v2);
                    }
                }
            }
        }
    }
    __syncthreads();

    // ---- P1.5: hw1 = h @ wg1 -> hw1T[d][i] (packed along i) ----
    {
        #pragma unroll
        for (int mt = 0; mt < 2; ++mt) {
            #pragma unroll
            for (int nn = 0; nn < 2; ++nn) {
                int cc = nn ? cc1 : cc0;
                f32x4 acc = {0.f, 0.f, 0.f, 0.f};
                #pragma unroll
                for (int ks = 0; ks < 4; ++ks) {
                    short8 a = *reinterpret_cast<const short8*>(
                        hs_b + swz(mt * 16 + lr, (ks * 32 + lq * 8) * 2));
                    short8 b = *reinterpret_cast<const short8*>(
                        wg1T + cc * 128 + ks * 32 + lq * 8);
                    acc = MFMA(a, b, acc);
                }
                uint2 pk;
                pk.x = f2bf2(acc[0], acc[1]);
                pk.y = f2bf2(acc[2], acc[3]);
                *reinterpret_cast<uint2*>(&hw1T[cc * SW1 + mt * 16 + lq * 4]) = pk;
            }
        }
    }
    __syncthreads();

    // ---- hoisted loop-invariant fragments ----
    short8 bh[2];      // (a') A: hw1T
    short8 bfr[2][4];  // (b)  B: wg2T
    #pragma unroll
    for (int nn = 0; nn < 2; ++nn) {
        int cc = nn ? cc1 : cc0;
        bh[nn] = *reinterpret_cast<const short8*>(&hw1T[cc * SW1 + lq * 8]);
        #pragma unroll
        for (int ks = 0; ks < 4; ++ks)
            bfr[nn][ks] = *reinterpret_cast<const short8*>(
                wg2T + cc * 128 + ks * 32 + lq * 8);
    }

    f32x4 facc[2][2];  // [nn(c2-tile)][it(i-tile)]
    #pragma unroll
    for (int i = 0; i < 2; ++i)
        #pragma unroll
        for (int j = 0; j < 2; ++j) facc[i][j] = f32x4{0.f, 0.f, 0.f, 0.f};

    // ---- P2: 12 chunks of 32 grid rows ----
    auto phase_a = [&](int ch) {   // a1 = silu(tg_ch @ hw1) -> a1R[ch&1]
        char* dst = gA_b + (ch & 1) * 8192;
        #pragma unroll
        for (int mt = 0; mt < 2; ++mt) {
            short8 tgf = *reinterpret_cast<const short8*>(
                tgp + (ch * 32 + mt * 16 + lr) * 32 + lq * 8);
            #pragma unroll
            for (int nn = 0; nn < 2; ++nn) {
                f32x4 acc = MFMA(bh[nn], tgf, f32x4{0.f, 0.f, 0.f, 0.f});
                uint2 pk;
                pk.x = f2bf2(silu_f(acc[0]), silu_f(acc[1]));
                pk.y = f2bf2(silu_f(acc[2]), silu_f(acc[3]));
                *reinterpret_cast<uint2*>(
                    dst + swz(mt * 16 + lr, (w * 2 + nn) * 32 + lq * 8)) = pk;
            }
        }
    };
    auto phase_b = [&](int ch) {   // a2 = silu(a1 @ wg2) -> gTl[c2][grow]
        const char* src = gA_b + (ch & 1) * 8192;
        #pragma unroll
        for (int mt = 0; mt < 2; ++mt) {
            f32x4 a0 = {0.f, 0.f, 0.f, 0.f}, a1v = {0.f, 0.f, 0.f, 0.f};
            #pragma unroll
            for (int ks = 0; ks < 4; ++ks) {
                short8 af = *reinterpret_cast<const short8*>(
                    src + swz(mt * 16 + lr, ks * 64 + lq * 16));
                a0 = MFMA(af, bfr[0][ks], a0);
                a1v = MFMA(af, bfr[1][ks], a1v);
            }
            uint2 p0, p1;
            p0.x = f2bf2(silu_f(a0[0]), silu_f(a0[1]));
            p0.y = f2bf2(silu_f(a0[2]), silu_f(a0[3]));
            p1.x = f2bf2(silu_f(a1v[0]), silu_f(a1v[1]));
            p1.y = f2bf2(silu_f(a1v[2]), silu_f(a1v[3]));
            *reinterpret_cast<uint2*>(&gTl[cc0 * SGT + mt * 16 + lq * 4]) = p0;
            *reinterpret_cast<uint2*>(&gTl[cc1 * SGT + mt * 16 + lq * 4]) = p1;
        }
    };
    auto phase_e = [&](int ch) {   // faccT[c2][i] += a2T @ fgT_ch
        #pragma unroll
        for (int it = 0; it < 2; ++it) {
            short8 bf_ = *reinterpret_cast<const short8*>(
                fgT + (it * 16 + lr) * 384 + ch * 32 + lq * 8);
            #pragma unroll
            for (int nn = 0; nn < 2; ++nn) {
                short8 ag = *reinterpret_cast<const short8*>(
                    &gTl[(nn ? cc1 : cc0) * SGT + lq * 8]);
                facc[nn][it] = MFMA(ag, bf_, facc[nn][it]);
            }
        }
    };

    // schedule: a(0) B {b(0),a(1)} B loop{ {e(k),a(k+2)} B b(k+1) B } tail
    phase_a(0);
    __syncthreads();
    phase_b(0);
    phase_a(1);
    __syncthreads();
    #pragma unroll 2
    for (int k = 0; k <= 9; ++k) {
        phase_e(k);
        phase_a(k + 2);
        __syncthreads();
        phase_b(k + 1);
        __syncthreads();
    }
    phase_e(10);
    __syncthreads();
    phase_b(11);
    __syncthreads();
    phase_e(11);

    // ---- P3a: pack faccT -> h2p[i][c2] row-major (xs area) ----
    #pragma unroll
    for (int nn = 0; nn < 2; ++nn)
        #pragma unroll
        for (int it = 0; it < 2; ++it) {
            uint2 pk;
            pk.x = f2bf2(facc[nn][it][0], facc[nn][it][1]);
            pk.y = f2bf2(facc[nn][it][2], facc[nn][it][3]);
            *reinterpret_cast<uint2*>(
                xs_b + swz(it * 16 + lr, (w * 2 + nn) * 32 + lq * 8)) = pk;
        }
    __syncthreads();

    // ---- P3b: h2 = wg3T(A) @ h2p(B); merge gate at i==0; pack h2R[i][c3] ----
    #pragma unroll
    for (int it = 0; it < 2; ++it) {
        #pragma unroll
        for (int nn = 0; nn < 2; ++nn) {
            int cc = nn ? cc1 : cc0;
            f32x4 acc = {0.f, 0.f, 0.f, 0.f};
            #pragma unroll
            for (int ks = 0; ks < 4; ++ks) {
                short8 a = *reinterpret_cast<const short8*>(
                    wg3T + cc * 128 + ks * 32 + lq * 8);
                short8 b = *reinterpret_cast<const short8*>(
                    xs_b + swz(it * 16 + lr, ks * 64 + lq * 16));
                acc = MFMA(a, b, acc);
            }
            if (it == 0 && lr == 0) acc = gate_v[nn];
            uint2 pk;
            pk.x = f2bf2(acc[0], acc[1]);
            pk.y = f2bf2(acc[2], acc[3]);
            *reinterpret_cast<uint2*>(
                hs_b + swz(it * 16 + lr, (w * 2 + nn) * 32 + lq * 8)) = pk;
        }
    }
    __syncthreads();

    // ---- P3c: out = so3lin2(h2R) + b2 on i==0 ----
    {
        const int m0[5] = {0, 1, 4, 9, 16};
        const int ml[5] = {1, 3, 5, 7, 9};
        #pragma unroll
        for (int l = 0; l < 5; ++l) {
            bool valid = lr < ml[l];
            #pragma unroll
            for (int nn = 0; nn < 2; ++nn) {
                int c = (w * 2 + nn) * 16 + lr;
                f32x4 acc = {0.f, 0.f, 0.f, 0.f};
                #pragma unroll
                for (int ks = 0; ks < 4; ++ks) {
                    short8 av = *reinterpret_cast<const short8*>(
                        hs_b + swz(m0[l] + lr, (ks * 32 + lq * 8) * 2));
                    short8 a = valid ? av : zero8;
                    short8 b = *reinterpret_cast<const short8*>(
                        w2T + (l * 128 + c) * 128 + ks * 32 + lq * 8);
                    acc = MFMA(a, b, acc);
                }
                #pragma unroll
                for (int r = 0; r < 4; ++r) {
                    int mm = lq * 4 + r;
                    if (mm < ml[l]) {
                        int i = m0[l] + mm;
                        float v2 = acc[r] + ((i == 0) ? bf2f(b2b[c]) : 0.f);
                        size_t o = (size_t)n * 3200 + i * 128 + c;
                        if (flag) ((u16*)outp)[o] = f2bf(v2);
                        else      ((float*)outp)[o] = v2;
                    }
                }
            }
        }
    }
}

extern "C" void kernel_launch(void* const* d_in, const int* in_sizes, int n_in,
                              void* d_out, int out_size, void* d_ws, size_t ws_size,
                              hipStream_t stream) {
    const void* x   = d_in[0];
    const void* w1  = d_in[1];
    const void* b1  = d_in[2];
    const void* wsm = d_in[3];
    const void* bs  = d_in[4];
    const void* wg1 = d_in[5];
    const void* wg2 = d_in[6];
    const void* wg3 = d_in[7];
    const void* w2  = d_in[8];
    const void* b2  = d_in[9];
    const void* tg  = d_in[10];
    const void* fg  = d_in[11];
    u16* wsp = (u16*)d_ws;
    u32* flagp = (u32*)(wsp + OFF_FLAG);

    detect_kernel<<<1, 64, 0, stream>>>(x, flagp);
    prep_kernel<<<(PREP_TOTAL + 255) / 256, 256, 0, stream>>>(
        w1, wg1, wg2, wg3, w2, tg, fg, wsm, b1, bs, b2, wsp, flagp);
    ffn_kernel<<<2048, 256, 0, stream>>>(x, wsp, d_out);
}